// Round 1
// baseline (1291.146 us; speedup 1.0000x reference)
//
#include <hip/hip_runtime.h>
#include <hip/hip_bf16.h>
#include <math.h>

#define EPSV 1e-5f

// ---------------- sizes ----------------
// B=32 Bc=16 L=2048 TOKEN=40 STRIDE=4 D=81 H=9 dk=9 S=512 FF=256 FC1=512 FC2=256 Y=4

// ---------------- K0: global min / (max-min) over x[:,20:2028) ----------------
__global__ void minmax_kernel(const float* __restrict__ x, float* __restrict__ scal) {
    __shared__ float smin[256], smax[256];
    int tid = threadIdx.x;
    float mn = 1e30f, mx = -1e30f;
    for (int i = tid; i < 32 * 2008; i += 256) {
        int b = i / 2008, c = i % 2008 + 20;
        float v = x[b * 2048 + c];
        mn = fminf(mn, v); mx = fmaxf(mx, v);
    }
    smin[tid] = mn; smax[tid] = mx; __syncthreads();
    for (int off = 128; off > 0; off >>= 1) {
        if (tid < off) { smin[tid] = fminf(smin[tid], smin[tid + off]); smax[tid] = fmaxf(smax[tid], smax[tid + off]); }
        __syncthreads();
    }
    if (tid == 0) { scal[0] = smin[0]; scal[1] = smax[0] - smin[0]; }
}

// ---------------- K1: tokenize + positional encoding ----------------
// txall: (48, 512, 81)  rows 0..31 = x, 32..47 = cali_spec
__global__ void tokenize_kernel(const float* __restrict__ x, const float* __restrict__ cali,
                                const float* __restrict__ scal, float* __restrict__ txall) {
    int idx = blockIdx.x * blockDim.x + threadIdx.x;
    if (idx >= 48 * 512 * 81) return;
    int d = idx % 81;
    int s = (idx / 81) % 512;
    int r = idx / (81 * 512);
    float xm = scal[0], inv_xs = 1.0f / scal[1];
    int col = s * 4 + d;     // padded position
    int oc = col - 40;
    float val = 0.0f;
    if (oc >= 0 && oc < 2048) {
        float sv = (r < 32) ? x[r * 2048 + oc] : cali[(r - 32) * 2048 + oc];
        val = (sv - xm) * inv_xs;
    }
    int j = d >> 1;
    float dv = expf(-9.210340371976184f * (2.0f * (float)j) / 81.0f);
    float ang = (float)s * dv;
    float pe = (d & 1) ? cosf(ang) : sinf(ang);
    txall[idx] = val + pe;
}

// ---------------- K2: Q2/Kc/Vc projections ----------------
// Q2[((s*9+h)*32+b)*9+d]   (b<32)
// Kc/Vc[((s*9+h)*48+k)*9+d] (k<48)
__global__ void qkv2_kernel(const float* __restrict__ txall,
                            const float* __restrict__ Wq2, const float* __restrict__ Wk2,
                            const float* __restrict__ Wv2,
                            float* __restrict__ Q2, float* __restrict__ Kc, float* __restrict__ Vc) {
    int blk = blockIdx.x;           // k*512 + s
    int k = blk >> 9, s = blk & 511;
    __shared__ float row[81];
    int tid = threadIdx.x;
    if (tid < 81) row[tid] = txall[(k * 512 + s) * 81 + tid];
    __syncthreads();
    for (int o = tid; o < 243; o += blockDim.x) {
        int t = o / 81; int hd = o % 81; int h = hd / 9, d = hd % 9;
        if (t == 0 && k >= 32) continue;
        const float* W = (t == 0) ? Wq2 : (t == 1) ? Wk2 : Wv2;
        const float* wp = W + h * 729 + d;
        float acc = 0.0f;
        #pragma unroll
        for (int e = 0; e < 81; e++) acc += row[e] * wp[e * 9];
        if (t == 0)      Q2[((s * 9 + h) * 32 + k) * 9 + d] = acc;
        else if (t == 1) Kc[((s * 9 + h) * 48 + k) * 9 + d] = acc;
        else             Vc[((s * 9 + h) * 48 + k) * 9 + d] = acc;
    }
}

// ---------------- K3: attention-2 (masked: key==b or key>=32) ----------------
// tmp2[(b*512+s)*81 + h*9+d]
__global__ void attn2_kernel(const float* __restrict__ Q2, const float* __restrict__ Kc,
                             const float* __restrict__ Vc, float* __restrict__ tmp2) {
    int tid = blockIdx.x * blockDim.x + threadIdx.x;
    if (tid >= 512 * 9 * 32) return;
    int b = tid & 31;
    int h = (tid >> 5) % 9;
    int s = tid / 288;
    const float* q = Q2 + ((s * 9 + h) * 32 + b) * 9;
    float qr[9];
    #pragma unroll
    for (int d = 0; d < 9; d++) qr[d] = q[d];
    const float* Kb = Kc + (s * 9 + h) * 48 * 9;
    const float* Vb = Vc + (s * 9 + h) * 48 * 9;
    float sc[17];
    float m = -1e30f;
    const float inv3 = 1.0f / 3.0f;
    #pragma unroll
    for (int j = 0; j < 17; j++) {
        int k = (j == 0) ? b : 31 + j;
        const float* kp = Kb + k * 9;
        float acc = 0.0f;
        #pragma unroll
        for (int d = 0; d < 9; d++) acc += qr[d] * kp[d];
        acc *= inv3;
        sc[j] = acc; m = fmaxf(m, acc);
    }
    float l = 0.0f, out[9];
    #pragma unroll
    for (int d = 0; d < 9; d++) out[d] = 0.0f;
    #pragma unroll
    for (int j = 0; j < 17; j++) {
        float p = __expf(sc[j] - m); l += p;
        int k = (j == 0) ? b : 31 + j;
        const float* vp = Vb + k * 9;
        #pragma unroll
        for (int d = 0; d < 9; d++) out[d] += p * vp[d];
    }
    float invl = 1.0f / l;
    float* op = tmp2 + (b * 512 + s) * 81 + h * 9;
    #pragma unroll
    for (int d = 0; d < 9; d++) op[d] = out[d] * invl;
}

// ---------------- K4: h2 = tmp2 @ Wo2 ; xh = tx + h2 ----------------
__global__ void h2xh_kernel(const float* __restrict__ tmp2, const float* __restrict__ Wo2,
                            const float* __restrict__ txall, float* __restrict__ h2,
                            float* __restrict__ xh) {
    int blk = blockIdx.x;     // b*512+s (b<32; same row index into txall)
    __shared__ float row[81];
    int tid = threadIdx.x;
    if (tid < 81) row[tid] = tmp2[blk * 81 + tid];
    __syncthreads();
    if (tid < 81) {
        float acc = 0.0f;
        #pragma unroll
        for (int e = 0; e < 81; e++) acc += row[e] * Wo2[e * 81 + tid];
        h2[blk * 81 + tid] = acc;
        xh[blk * 81 + tid] = txall[blk * 81 + tid] + acc;
    }
}

// ---------------- K5: Qs/Ks projections  (Vs == Qs in the reference!) ----------------
// Qs/Ks[((b*9+h)*512+s)*9+d]
__global__ void qks_kernel(const float* __restrict__ xh, const float* __restrict__ Wq,
                           const float* __restrict__ Wk, float* __restrict__ Qs,
                           float* __restrict__ Ks) {
    int blk = blockIdx.x;     // b*512+s
    int b = blk >> 9, s = blk & 511;
    __shared__ float row[81];
    int tid = threadIdx.x;
    if (tid < 81) row[tid] = xh[blk * 81 + tid];
    __syncthreads();
    for (int o = tid; o < 162; o += blockDim.x) {
        int t = o / 81; int hd = o % 81; int h = hd / 9, d = hd % 9;
        const float* wp = ((t == 0) ? Wq : Wk) + h * 729 + d;
        float acc = 0.0f;
        #pragma unroll
        for (int e = 0; e < 81; e++) acc += row[e] * wp[e * 9];
        float* dst = (t == 0) ? Qs : Ks;
        dst[((b * 9 + h) * 512 + s) * 9 + d] = acc;
    }
}

// ---------------- K6: biasT[t*512+s] = (corr_map @ Cv)[s,t] / sqrt(512) ----------------
__global__ void biasmm_kernel(const float* __restrict__ corr, const float* __restrict__ Cv,
                              float* __restrict__ biasT) {
    __shared__ float As[16][17];   // As[kk][tt] = Cv[(k0+kk)*512 + t0+tt]
    __shared__ float Bs[16][17];   // Bs[ss][kk] = corr[(s0+ss)*512 + k0+kk]
    int tx = threadIdx.x, ty = threadIdx.y;
    int t0 = blockIdx.x * 16, s0 = blockIdx.y * 16;
    float acc = 0.0f;
    for (int k0 = 0; k0 < 512; k0 += 16) {
        As[ty][tx] = Cv[(k0 + ty) * 512 + (t0 + tx)];
        Bs[ty][tx] = corr[(s0 + ty) * 512 + (k0 + tx)];
        __syncthreads();
        #pragma unroll
        for (int kk = 0; kk < 16; kk++) acc += As[kk][ty] * Bs[tx][kk];
        __syncthreads();
    }
    const float invs = 0.04419417382415922f;   // 1/sqrt(512)
    biasT[(t0 + ty) * 512 + (s0 + tx)] = acc * invs;
}

// ---------------- K7: attention-1, flash-style online softmax ----------------
// one block per (b,h), one thread per query row s
__global__ __launch_bounds__(512) void attn1_kernel(const float* __restrict__ Qs,
                                                    const float* __restrict__ Ks,
                                                    const float* __restrict__ biasT,
                                                    const float* __restrict__ cwp,
                                                    float* __restrict__ h1tmp) {
    int bh = blockIdx.x;   // b*9+h
    int b = bh / 9, h = bh % 9;
    __shared__ float Ksh[512][9];
    __shared__ float Vsh[512][9];
    int tid = threadIdx.x;
    const float* Kb = Ks + bh * 512 * 9;
    const float* Qb = Qs + bh * 512 * 9;
    for (int i = tid; i < 512 * 9; i += 512) {
        Ksh[i / 9][i % 9] = Kb[i];
        Vsh[i / 9][i % 9] = Qb[i];   // Vs == Qs
    }
    __syncthreads();
    float q[9];
    #pragma unroll
    for (int d = 0; d < 9; d++) q[d] = Vsh[tid][d];
    float cw = cwp[0];
    float c1 = (1.0f - cw) / 3.0f;
    float m = -1e30f, l = 0.0f;
    float acc[9];
    #pragma unroll
    for (int d = 0; d < 9; d++) acc[d] = 0.0f;
    for (int t = 0; t < 512; t++) {
        float scr = 0.0f;
        #pragma unroll
        for (int d = 0; d < 9; d++) scr += q[d] * Ksh[t][d];
        scr = c1 * scr + cw * biasT[t * 512 + tid];
        float nm = fmaxf(m, scr);
        float f = __expf(m - nm);
        float p = __expf(scr - nm);
        l = l * f + p;
        #pragma unroll
        for (int d = 0; d < 9; d++) acc[d] = acc[d] * f + p * Vsh[t][d];
        m = nm;
    }
    float invl = 1.0f / l;
    float* op = h1tmp + (b * 512 + tid) * 81 + h * 9;
    #pragma unroll
    for (int d = 0; d < 9; d++) op[d] = acc[d] * invl;
}

// ---------------- K8: matin = (1-hw)*(h1tmp@Wo1) + hw*h2 + tx ----------------
__global__ void h1o_kernel(const float* __restrict__ h1tmp, const float* __restrict__ Wo1,
                           const float* __restrict__ h2, const float* __restrict__ txall,
                           const float* __restrict__ hwp, float* __restrict__ matin) {
    int blk = blockIdx.x;
    __shared__ float row[81];
    int tid = threadIdx.x;
    if (tid < 81) row[tid] = h1tmp[blk * 81 + tid];
    __syncthreads();
    if (tid < 81) {
        float acc = 0.0f;
        #pragma unroll
        for (int e = 0; e < 81; e++) acc += row[e] * Wo1[e * 81 + tid];
        float hw = hwp[0];
        float att = (1.0f - hw) * acc + hw * h2[blk * 81 + tid];
        matin[blk * 81 + tid] = att + txall[blk * 81 + tid];
    }
}

// ---------------- stats: per-channel sum / sumsq via atomics ----------------
__global__ void stats_kernel(const float* __restrict__ in, float* __restrict__ st,
                             int total, int C) {
    __shared__ float ssum[512], ssq[512];
    int tid = threadIdx.x;
    for (int c = tid; c < C; c += blockDim.x) { ssum[c] = 0.0f; ssq[c] = 0.0f; }
    __syncthreads();
    for (int f = blockIdx.x * blockDim.x + tid; f < total; f += gridDim.x * blockDim.x) {
        float v = in[f]; int c = f % C;
        atomicAdd(&ssum[c], v); atomicAdd(&ssq[c], v * v);
    }
    __syncthreads();
    for (int c = tid; c < C; c += blockDim.x) {
        atomicAdd(&st[c], ssum[c]); atomicAdd(&st[C + c], ssq[c]);
    }
}

// ---------------- bn apply (elementwise; in-place safe) ----------------
__global__ void bn_apply_kernel(const float* __restrict__ in, float* __restrict__ out,
                                const float* __restrict__ st, const float* __restrict__ g,
                                const float* __restrict__ bta, int total, int C, float invN) {
    int f = blockIdx.x * blockDim.x + threadIdx.x;
    if (f >= total) return;
    int c = f % C;
    float mean = st[c] * invN;
    float var = st[C + c] * invN - mean * mean;
    out[f] = (in[f] - mean) * rsqrtf(var + EPSV) * g[c] + bta[c];
}

// ---------------- K11: f1 = relu(ma @ ff1_w + ff1_b)   (81 -> 256) ----------------
__global__ void ff1_kernel(const float* __restrict__ ma, const float* __restrict__ W,
                           const float* __restrict__ bias, float* __restrict__ f1) {
    int blk = blockIdx.x;
    __shared__ float row[81];
    int tid = threadIdx.x;   // 256
    if (tid < 81) row[tid] = ma[blk * 81 + tid];
    __syncthreads();
    float acc = bias[tid];
    #pragma unroll
    for (int e = 0; e < 81; e++) acc += row[e] * W[e * 256 + tid];
    f1[blk * 256 + tid] = fmaxf(acc, 0.0f);
}

// ---------------- K12: t3 = ma + relu( bn2(f1) @ ff2_w + ff2_b )  (256 -> 81) ----------------
__global__ void ff2_kernel(const float* __restrict__ f1, const float* __restrict__ st2,
                           const float* __restrict__ g2, const float* __restrict__ b2,
                           const float* __restrict__ W, const float* __restrict__ bias,
                           const float* __restrict__ ma, float* __restrict__ t3, float invN) {
    int blk = blockIdx.x;
    __shared__ float row[256];
    int tid = threadIdx.x;   // 256
    {
        float v = f1[blk * 256 + tid];
        float mean = st2[tid] * invN;
        float var = st2[256 + tid] * invN - mean * mean;
        row[tid] = (v - mean) * rsqrtf(var + EPSV) * g2[tid] + b2[tid];
    }
    __syncthreads();
    if (tid < 81) {
        float acc = bias[tid];
        #pragma unroll 8
        for (int e = 0; e < 256; e++) acc += row[e] * W[e * 81 + tid];
        t3[blk * 81 + tid] = ma[blk * 81 + tid] + fmaxf(acc, 0.0f);
    }
}

// ---------------- K13: token pooling -> fea ----------------
__global__ void token_kernel(const float* __restrict__ t3, const float* __restrict__ st3,
                             const float* __restrict__ g3, const float* __restrict__ b3,
                             const float* __restrict__ tvw, const float* __restrict__ tvb,
                             const float* __restrict__ beta1, const float* __restrict__ basel,
                             const float* __restrict__ a1p, const float* __restrict__ a2p,
                             float* __restrict__ fea, float invN) {
    int blk = blockIdx.x;   // b*512+s
    int b = blk >> 9, s = blk & 511;
    __shared__ float row[81];
    __shared__ float u[81], v[81];
    __shared__ float red[128];
    int tid = threadIdx.x;   // 128
    if (tid < 81) {
        float x = t3[blk * 81 + tid];
        float mean = st3[tid] * invN;
        float var = st3[81 + tid] * invN - mean * mean;
        row[tid] = (x - mean) * rsqrtf(var + EPSV) * g3[tid] + b3[tid];
    }
    __syncthreads();
    if (tid < 81) {
        float au = tvb[tid], av = 0.0f;
        #pragma unroll
        for (int e = 0; e < 81; e++) {
            float r = row[e];
            au += r * tvw[e * 81 + tid];
            av += r * beta1[e * 81 + tid];
        }
        u[tid] = au; v[tid] = av;
    }
    __syncthreads();
    float myv = (tid < 81) ? v[tid] : -1e30f;
    red[tid] = myv; __syncthreads();
    for (int off = 64; off > 0; off >>= 1) {
        if (tid < off) red[tid] = fmaxf(red[tid], red[tid + off]);
        __syncthreads();
    }
    float mx = red[0]; __syncthreads();
    float p = (tid < 81) ? __expf(v[tid] - mx) : 0.0f;
    float up = (tid < 81) ? u[tid] * p : 0.0f;
    red[tid] = p; __syncthreads();
    for (int off = 64; off > 0; off >>= 1) {
        if (tid < off) red[tid] += red[tid + off];
        __syncthreads();
    }
    float l = red[0]; __syncthreads();
    red[tid] = up; __syncthreads();
    for (int off = 64; off > 0; off >>= 1) {
        if (tid < off) red[tid] += red[tid + off];
        __syncthreads();
    }
    if (tid == 0) {
        float a = red[0] / l;
        fea[blk] = a1p[0] * a + a2p[0] * basel[b * 2048 + s * 4];
    }
}

// ---------------- small FC: out = act(in @ W + b) ; in (32,K), W (K,N) ----------------
__global__ void fc_kernel(const float* __restrict__ in, const float* __restrict__ W,
                          const float* __restrict__ bias, float* __restrict__ out,
                          int K, int N, int mode) {
    int idx = blockIdx.x * blockDim.x + threadIdx.x;
    if (idx >= 32 * N) return;
    int b = idx / N, j = idx % N;
    float acc = bias[j];
    const float* ip = in + b * K;
    for (int k = 0; k < K; k++) acc += ip[k] * W[k * N + j];
    if (mode == 1) acc = fmaxf(acc, 0.0f);
    else if (mode == 2) acc = tanhf(acc);
    out[idx] = acc;
}

// =======================================================================
extern "C" void kernel_launch(void* const* d_in, const int* in_sizes, int n_in,
                              void* d_out, int out_size, void* d_ws, size_t ws_size,
                              hipStream_t stream) {
    const float* x       = (const float*)d_in[0];
    const float* basel   = (const float*)d_in[1];
    const float* cali    = (const float*)d_in[2];
    const float* Wq      = (const float*)d_in[3];
    const float* Wk      = (const float*)d_in[4];
    const float* Wq2     = (const float*)d_in[5];
    const float* Wk2     = (const float*)d_in[6];
    const float* Wv2     = (const float*)d_in[7];
    const float* Cv      = (const float*)d_in[8];
    const float* Wo1     = (const float*)d_in[9];
    const float* Wo2     = (const float*)d_in[10];
    const float* corr_w  = (const float*)d_in[11];
    const float* h_w     = (const float*)d_in[12];
    const float* corr    = (const float*)d_in[13];
    const float* g1      = (const float*)d_in[14];
    const float* b1      = (const float*)d_in[15];
    const float* ff1_w   = (const float*)d_in[16];
    const float* ff1_b   = (const float*)d_in[17];
    const float* g2      = (const float*)d_in[18];
    const float* b2      = (const float*)d_in[19];
    const float* ff2_w   = (const float*)d_in[20];
    const float* ff2_b   = (const float*)d_in[21];
    const float* g3      = (const float*)d_in[22];
    const float* b3      = (const float*)d_in[23];
    const float* tvw     = (const float*)d_in[24];
    const float* tvb     = (const float*)d_in[25];
    const float* beta1   = (const float*)d_in[26];
    const float* a1      = (const float*)d_in[27];
    const float* a2      = (const float*)d_in[28];
    const float* fc1_w   = (const float*)d_in[29];
    const float* fc1_b   = (const float*)d_in[30];
    const float* bnf1_g  = (const float*)d_in[31];
    const float* bnf1_b  = (const float*)d_in[32];
    const float* fc2_w   = (const float*)d_in[33];
    const float* fc2_b   = (const float*)d_in[34];
    const float* bnf2_g  = (const float*)d_in[35];
    const float* bnf2_b  = (const float*)d_in[36];
    const float* fc3_w   = (const float*)d_in[37];
    const float* fc3_b   = (const float*)d_in[38];
    float* out = (float*)d_out;
    float* ws = (float*)d_ws;

    // ---- workspace layout (float offsets) ----
    const size_t SCAL  = 0;        // 2
    const size_t ST1   = 32;       // 162  (C=81)
    const size_t ST2   = 200;      // 512  (C=256)
    const size_t ST3   = 720;      // 162  (C=81)
    const size_t ST4   = 900;      // 1024 (C=512)
    const size_t ST5   = 1930;     // 512  (C=256)
    const size_t FEA   = 4096;     // 16384
    const size_t FCH1  = 20480;    // 16384
    const size_t FCH2  = 36864;    // 8192
    const size_t TX    = 49152;    // 1990656
    const size_t Q2O   = 2039808;  // 1327104   (reused: h1tmp)
    const size_t KCO   = 3366912;  // 1990656   (reused: Qs)
    const size_t VCO   = 5357568;  // 1990656   (reused: Ks)
    const size_t TMP2  = 7348224;  // 1327104   (reused: matin)
    const size_t H2O   = 8675328;  // 1327104   (reused: t3)
    const size_t XHO   = 10002432; // 1327104   (reused: ma)
    const size_t BIASO = 11329536; // 262144
    const size_t F1O   = 11591680; // 4194304
    // total ~15.79M floats = 63.2 MB

    float* scal  = ws + SCAL;
    float* st1   = ws + ST1;
    float* st2   = ws + ST2;
    float* st3   = ws + ST3;
    float* st4   = ws + ST4;
    float* st5   = ws + ST5;
    float* fea   = ws + FEA;
    float* fch1  = ws + FCH1;
    float* fch2  = ws + FCH2;
    float* txall = ws + TX;
    float* Q2    = ws + Q2O;
    float* Kc    = ws + KCO;
    float* Vc    = ws + VCO;
    float* tmp2  = ws + TMP2;
    float* h2    = ws + H2O;
    float* xh    = ws + XHO;
    float* biasT = ws + BIASO;
    float* f1    = ws + F1O;
    float* h1tmp = Q2;     // reuse
    float* Qs    = Kc;     // reuse
    float* Ks    = Vc;     // reuse
    float* matin = tmp2;   // reuse
    float* t3    = h2;     // reuse
    float* ma    = xh;     // reuse

    // zero the stats accumulators (atomics target) — capture-safe
    hipMemsetAsync(ws + ST1, 0, (ST5 + 512 - ST1) * sizeof(float), stream);

    minmax_kernel<<<1, 256, 0, stream>>>(x, scal);

    tokenize_kernel<<<(48 * 512 * 81 + 255) / 256, 256, 0, stream>>>(x, cali, scal, txall);

    qkv2_kernel<<<48 * 512, 256, 0, stream>>>(txall, Wq2, Wk2, Wv2, Q2, Kc, Vc);

    attn2_kernel<<<(512 * 9 * 32) / 256, 256, 0, stream>>>(Q2, Kc, Vc, tmp2);

    h2xh_kernel<<<32 * 512, 128, 0, stream>>>(tmp2, Wo2, txall, h2, xh);

    qks_kernel<<<32 * 512, 256, 0, stream>>>(xh, Wq, Wk, Qs, Ks);

    biasmm_kernel<<<dim3(32, 32), dim3(16, 16), 0, stream>>>(corr, Cv, biasT);

    attn1_kernel<<<288, 512, 0, stream>>>(Qs, Ks, biasT, corr_w, h1tmp);

    h1o_kernel<<<32 * 512, 128, 0, stream>>>(h1tmp, Wo1, h2, txall, h_w, matin);

    // BN1 over (B,S) per D-channel
    stats_kernel<<<256, 256, 0, stream>>>(matin, st1, 16384 * 81, 81);
    bn_apply_kernel<<<(16384 * 81 + 255) / 256, 256, 0, stream>>>(matin, ma, st1, g1, b1,
                                                                  16384 * 81, 81, 1.0f / 16384.0f);

    ff1_kernel<<<16384, 256, 0, stream>>>(ma, ff1_w, ff1_b, f1);

    stats_kernel<<<256, 256, 0, stream>>>(f1, st2, 16384 * 256, 256);

    ff2_kernel<<<16384, 256, 0, stream>>>(f1, st2, g2, b2, ff2_w, ff2_b, ma, t3, 1.0f / 16384.0f);

    stats_kernel<<<256, 256, 0, stream>>>(t3, st3, 16384 * 81, 81);

    token_kernel<<<16384, 128, 0, stream>>>(t3, st3, g3, b3, tvw, tvb, beta1, basel, a1, a2,
                                            fea, 1.0f / 16384.0f);

    // FC head
    fc_kernel<<<(32 * 512 + 255) / 256, 256, 0, stream>>>(fea, fc1_w, fc1_b, fch1, 512, 512, 1);
    stats_kernel<<<32, 256, 0, stream>>>(fch1, st4, 32 * 512, 512);
    bn_apply_kernel<<<(32 * 512 + 255) / 256, 256, 0, stream>>>(fch1, fch1, st4, bnf1_g, bnf1_b,
                                                                32 * 512, 512, 1.0f / 32.0f);

    fc_kernel<<<(32 * 256 + 255) / 256, 256, 0, stream>>>(fch1, fc2_w, fc2_b, fch2, 512, 256, 1);
    stats_kernel<<<16, 256, 0, stream>>>(fch2, st5, 32 * 256, 256);
    bn_apply_kernel<<<(32 * 256 + 255) / 256, 256, 0, stream>>>(fch2, fch2, st5, bnf2_g, bnf2_b,
                                                                32 * 256, 256, 1.0f / 32.0f);

    fc_kernel<<<1, 128, 0, stream>>>(fch2, fc3_w, fc3_b, out, 256, 4, 2);
}

// Round 2
// 656.316 us; speedup vs baseline: 1.9673x; 1.9673x over previous
//
#include <hip/hip_runtime.h>
#include <hip/hip_bf16.h>
#include <math.h>

#define EPSV 1e-5f

// ---------------- sizes ----------------
// B=32 Bc=16 L=2048 TOKEN=40 STRIDE=4 D=81 H=9 dk=9 S=512 FF=256 FC1=512 FC2=256 Y=4

// ---------------- minmax: two-stage ----------------
__global__ void minmax_part(const float* __restrict__ x, float* __restrict__ part) {
    __shared__ float smin[256], smax[256];
    int tid = threadIdx.x;
    float mn = 1e30f, mx = -1e30f;
    for (int i = blockIdx.x * 256 + tid; i < 32 * 2008; i += 64 * 256) {
        int b = i / 2008, c = i % 2008 + 20;
        float v = x[b * 2048 + c];
        mn = fminf(mn, v); mx = fmaxf(mx, v);
    }
    smin[tid] = mn; smax[tid] = mx; __syncthreads();
    for (int off = 128; off > 0; off >>= 1) {
        if (tid < off) { smin[tid] = fminf(smin[tid], smin[tid + off]); smax[tid] = fmaxf(smax[tid], smax[tid + off]); }
        __syncthreads();
    }
    if (tid == 0) { part[blockIdx.x] = smin[0]; part[64 + blockIdx.x] = smax[0]; }
}

__global__ void minmax_fin(const float* __restrict__ part, float* __restrict__ scal) {
    __shared__ float smn[64], smx[64];
    int tid = threadIdx.x;
    smn[tid] = part[tid]; smx[tid] = part[64 + tid]; __syncthreads();
    for (int off = 32; off > 0; off >>= 1) {
        if (tid < off) { smn[tid] = fminf(smn[tid], smn[tid + off]); smx[tid] = fmaxf(smx[tid], smx[tid + off]); }
        __syncthreads();
    }
    if (tid == 0) { scal[0] = smn[0]; scal[1] = smx[0] - smn[0]; }
}

// ---------------- PE table (512 x 81) ----------------
__global__ void pe_kernel(float* __restrict__ pe) {
    int idx = blockIdx.x * blockDim.x + threadIdx.x;
    if (idx >= 512 * 81) return;
    int d = idx % 81, s = idx / 81;
    int j = d >> 1;
    float dv = __expf(-9.210340371976184f * (2.0f * (float)j) / 81.0f);
    float ang = (float)s * dv;
    pe[idx] = (d & 1) ? cosf(ang) : sinf(ang);
}

// ---------------- tokenize + add PE ----------------
// txall: (48, 512, 81)  rows 0..31 = x, 32..47 = cali_spec
__global__ void tokenize_kernel(const float* __restrict__ x, const float* __restrict__ cali,
                                const float* __restrict__ scal, const float* __restrict__ pe,
                                float* __restrict__ txall) {
    int idx = blockIdx.x * blockDim.x + threadIdx.x;
    if (idx >= 48 * 512 * 81) return;
    int d = idx % 81;
    int s = (idx / 81) % 512;
    int r = idx / (81 * 512);
    float xm = scal[0], inv_xs = 1.0f / scal[1];
    int oc = s * 4 + d - 40;
    float val = 0.0f;
    if (oc >= 0 && oc < 2048) {
        float sv = (r < 32) ? x[r * 2048 + oc] : cali[(r - 32) * 2048 + oc];
        val = (sv - xm) * inv_xs;
    }
    txall[idx] = val + pe[s * 81 + d];
}

// ---------------- qkv2: 64 rows/block, W in LDS, 4-row reg tile ----------------
// Q2[((s*9+h)*32+b)*9+d]   Kc/Vc[((s*9+h)*48+k)*9+d]
__global__ __launch_bounds__(256) void qkv2_kernel(const float* __restrict__ txall,
                            const float* __restrict__ Wq2, const float* __restrict__ Wk2,
                            const float* __restrict__ Wv2,
                            float* __restrict__ Q2, float* __restrict__ Kc, float* __restrict__ Vc) {
    __shared__ float rows_[64 * 81];
    __shared__ float Wl[6561];
    int blk = blockIdx.x;            // 0..383
    int row0 = blk * 64;             // k*512+s flattened
    int k = row0 >> 9;               // block-uniform
    int s0 = row0 & 511;
    int tid = threadIdx.x;
    for (int i = tid; i < 64 * 81; i += 256) rows_[i] = txall[row0 * 81 + i];
    for (int t = 0; t < 3; t++) {
        if (t == 0 && k >= 32) continue;   // block-uniform: no divergent barrier
        const float* W = (t == 0) ? Wq2 : (t == 1) ? Wk2 : Wv2;
        __syncthreads();
        for (int i = tid; i < 6561; i += 256) {
            int e = i / 81, hd = i % 81, h = hd / 9, d = hd % 9;
            Wl[i] = W[h * 729 + e * 9 + d];     // Wl[e*81+hd]
        }
        __syncthreads();
        for (int o = tid; o < 16 * 81; o += 256) {
            int r4 = o / 81, hd = o % 81;
            float a0 = 0, a1 = 0, a2 = 0, a3 = 0;
            const float* rp = rows_ + r4 * 4 * 81;
            #pragma unroll 3
            for (int e = 0; e < 81; e++) {
                float w = Wl[e * 81 + hd];
                a0 += rp[e] * w; a1 += rp[81 + e] * w;
                a2 += rp[162 + e] * w; a3 += rp[243 + e] * w;
            }
            int h = hd / 9, d = hd % 9;
            int sb = s0 + r4 * 4;
            float av[4] = {a0, a1, a2, a3};
            #pragma unroll
            for (int j = 0; j < 4; j++) {
                int s = sb + j;
                if (t == 0)      Q2[((s * 9 + h) * 32 + k) * 9 + d] = av[j];
                else if (t == 1) Kc[((s * 9 + h) * 48 + k) * 9 + d] = av[j];
                else             Vc[((s * 9 + h) * 48 + k) * 9 + d] = av[j];
            }
        }
    }
}

// ---------------- attention-2 (masked: key==b or key>=32) ----------------
__global__ void attn2_kernel(const float* __restrict__ Q2, const float* __restrict__ Kc,
                             const float* __restrict__ Vc, float* __restrict__ tmp2) {
    int tid = blockIdx.x * blockDim.x + threadIdx.x;
    if (tid >= 512 * 9 * 32) return;
    int b = tid & 31;
    int h = (tid >> 5) % 9;
    int s = tid / 288;
    const float* q = Q2 + ((s * 9 + h) * 32 + b) * 9;
    float qr[9];
    #pragma unroll
    for (int d = 0; d < 9; d++) qr[d] = q[d];
    const float* Kb = Kc + (s * 9 + h) * 48 * 9;
    const float* Vb = Vc + (s * 9 + h) * 48 * 9;
    float sc[17];
    float m = -1e30f;
    const float inv3 = 1.0f / 3.0f;
    #pragma unroll
    for (int j = 0; j < 17; j++) {
        int k = (j == 0) ? b : 31 + j;
        const float* kp = Kb + k * 9;
        float acc = 0.0f;
        #pragma unroll
        for (int d = 0; d < 9; d++) acc += qr[d] * kp[d];
        acc *= inv3;
        sc[j] = acc; m = fmaxf(m, acc);
    }
    float l = 0.0f, outv[9];
    #pragma unroll
    for (int d = 0; d < 9; d++) outv[d] = 0.0f;
    #pragma unroll
    for (int j = 0; j < 17; j++) {
        float p = __expf(sc[j] - m); l += p;
        int k = (j == 0) ? b : 31 + j;
        const float* vp = Vb + k * 9;
        #pragma unroll
        for (int d = 0; d < 9; d++) outv[d] += p * vp[d];
    }
    float invl = 1.0f / l;
    float* op = tmp2 + (b * 512 + s) * 81 + h * 9;
    #pragma unroll
    for (int d = 0; d < 9; d++) op[d] = outv[d] * invl;
}

// ---------------- h2 = tmp2 @ Wo2 ; xh = tx + h2  (64 rows/block) ----------------
__global__ __launch_bounds__(256) void h2xh_kernel(const float* __restrict__ tmp2,
                            const float* __restrict__ Wo2, const float* __restrict__ txall,
                            float* __restrict__ h2, float* __restrict__ xh) {
    __shared__ float rows_[64 * 81];
    __shared__ float Wl[6561];
    int row0 = blockIdx.x * 64;
    int tid = threadIdx.x;
    for (int i = tid; i < 64 * 81; i += 256) rows_[i] = tmp2[row0 * 81 + i];
    for (int i = tid; i < 6561; i += 256) Wl[i] = Wo2[i];
    __syncthreads();
    for (int o = tid; o < 16 * 81; o += 256) {
        int r4 = o / 81, c = o % 81;
        float a0 = 0, a1 = 0, a2 = 0, a3 = 0;
        const float* rp = rows_ + r4 * 4 * 81;
        #pragma unroll 3
        for (int e = 0; e < 81; e++) {
            float w = Wl[e * 81 + c];
            a0 += rp[e] * w; a1 += rp[81 + e] * w;
            a2 += rp[162 + e] * w; a3 += rp[243 + e] * w;
        }
        float av[4] = {a0, a1, a2, a3};
        #pragma unroll
        for (int j = 0; j < 4; j++) {
            int idx = (row0 + r4 * 4 + j) * 81 + c;
            h2[idx] = av[j];
            xh[idx] = txall[idx] + av[j];
        }
    }
}

// ---------------- Qs/Ks projections (Vs == Qs) ----------------
// Qs/Ks[((b*9+h)*512+s)*9+d]
__global__ __launch_bounds__(256) void qks_kernel(const float* __restrict__ xh,
                           const float* __restrict__ Wq, const float* __restrict__ Wk,
                           float* __restrict__ Qs, float* __restrict__ Ks) {
    __shared__ float rows_[64 * 81];
    __shared__ float Wl[6561];
    int blk = blockIdx.x;            // 0..255
    int row0 = blk * 64;             // b*512+s
    int b = row0 >> 9;
    int s0 = row0 & 511;
    int tid = threadIdx.x;
    for (int i = tid; i < 64 * 81; i += 256) rows_[i] = xh[row0 * 81 + i];
    for (int t = 0; t < 2; t++) {
        const float* W = (t == 0) ? Wq : Wk;
        __syncthreads();
        for (int i = tid; i < 6561; i += 256) {
            int e = i / 81, hd = i % 81, h = hd / 9, d = hd % 9;
            Wl[i] = W[h * 729 + e * 9 + d];
        }
        __syncthreads();
        float* dst = (t == 0) ? Qs : Ks;
        for (int o = tid; o < 16 * 81; o += 256) {
            int r4 = o / 81, hd = o % 81;
            float a0 = 0, a1 = 0, a2 = 0, a3 = 0;
            const float* rp = rows_ + r4 * 4 * 81;
            #pragma unroll 3
            for (int e = 0; e < 81; e++) {
                float w = Wl[e * 81 + hd];
                a0 += rp[e] * w; a1 += rp[81 + e] * w;
                a2 += rp[162 + e] * w; a3 += rp[243 + e] * w;
            }
            int h = hd / 9, d = hd % 9;
            int sb = s0 + r4 * 4;
            float av[4] = {a0, a1, a2, a3};
            #pragma unroll
            for (int j = 0; j < 4; j++)
                dst[((b * 9 + h) * 512 + (sb + j)) * 9 + d] = av[j];
        }
    }
}

// ---------------- biasT = (corr @ Cv)^T / sqrt(S): 32x32 tile, 2x2/thread ----------------
__global__ __launch_bounds__(256) void biasmm_kernel(const float* __restrict__ corr,
                              const float* __restrict__ Cv, float* __restrict__ biasT) {
    __shared__ float As[32][33];   // As[kk][tt] = Cv[(k0+kk)*512 + t0+tt]
    __shared__ float Bs[32][33];   // Bs[ss][kk] = corr[(s0+ss)*512 + k0+kk]
    int tx = threadIdx.x, ty = threadIdx.y;   // 16 x 16
    int tid = ty * 16 + tx;
    int t0 = blockIdx.y * 32, s0 = blockIdx.x * 32;
    float a00 = 0, a01 = 0, a10 = 0, a11 = 0;   // [tt-half][ss-half]
    for (int k0 = 0; k0 < 512; k0 += 32) {
        for (int ii = tid; ii < 1024; ii += 256) {
            int r = ii >> 5, c = ii & 31;
            As[r][c] = Cv[(k0 + r) * 512 + t0 + c];
            Bs[r][c] = corr[(s0 + r) * 512 + k0 + c];
        }
        __syncthreads();
        #pragma unroll
        for (int kk = 0; kk < 32; kk++) {
            float b0 = Bs[tx][kk], b1 = Bs[tx + 16][kk];
            float c0 = As[kk][ty], c1 = As[kk][ty + 16];
            a00 += c0 * b0; a01 += c0 * b1; a10 += c1 * b0; a11 += c1 * b1;
        }
        __syncthreads();
    }
    const float invs = 0.04419417382415922f;   // 1/sqrt(512)
    biasT[(t0 + ty) * 512 + s0 + tx]            = a00 * invs;
    biasT[(t0 + ty) * 512 + s0 + tx + 16]       = a01 * invs;
    biasT[(t0 + ty + 16) * 512 + s0 + tx]       = a10 * invs;
    biasT[(t0 + ty + 16) * 512 + s0 + tx + 16]  = a11 * invs;
}

// ---------------- attention-1, flash-style online softmax ----------------
__global__ __launch_bounds__(512) void attn1_kernel(const float* __restrict__ Qs,
                                                    const float* __restrict__ Ks,
                                                    const float* __restrict__ biasT,
                                                    const float* __restrict__ cwp,
                                                    float* __restrict__ h1tmp) {
    int bh = blockIdx.x;   // b*9+h
    int b = bh / 9, h = bh % 9;
    __shared__ float Ksh[512][9];
    __shared__ float Vsh[512][9];
    int tid = threadIdx.x;
    const float* Kb = Ks + bh * 512 * 9;
    const float* Qb = Qs + bh * 512 * 9;
    for (int i = tid; i < 512 * 9; i += 512) {
        Ksh[i / 9][i % 9] = Kb[i];
        Vsh[i / 9][i % 9] = Qb[i];   // Vs == Qs
    }
    __syncthreads();
    float q[9];
    #pragma unroll
    for (int d = 0; d < 9; d++) q[d] = Vsh[tid][d];
    float cw = cwp[0];
    float c1 = (1.0f - cw) / 3.0f;
    float m = -1e30f, l = 0.0f;
    float acc[9];
    #pragma unroll
    for (int d = 0; d < 9; d++) acc[d] = 0.0f;
    for (int t = 0; t < 512; t++) {
        float scr = 0.0f;
        #pragma unroll
        for (int d = 0; d < 9; d++) scr += q[d] * Ksh[t][d];
        scr = c1 * scr + cw * biasT[t * 512 + tid];
        float nm = fmaxf(m, scr);
        float f = __expf(m - nm);
        float p = __expf(scr - nm);
        l = l * f + p;
        #pragma unroll
        for (int d = 0; d < 9; d++) acc[d] = acc[d] * f + p * Vsh[t][d];
        m = nm;
    }
    float invl = 1.0f / l;
    float* op = h1tmp + (b * 512 + tid) * 81 + h * 9;
    #pragma unroll
    for (int d = 0; d < 9; d++) op[d] = acc[d] * invl;
}

// ---------------- matin = (1-hw)*(h1tmp@Wo1) + hw*h2 + tx  (64 rows/block) ----------------
__global__ __launch_bounds__(256) void h1o_kernel(const float* __restrict__ h1tmp,
                           const float* __restrict__ Wo1, const float* __restrict__ h2,
                           const float* __restrict__ txall, const float* __restrict__ hwp,
                           float* __restrict__ matin) {
    __shared__ float rows_[64 * 81];
    __shared__ float Wl[6561];
    int row0 = blockIdx.x * 64;
    int tid = threadIdx.x;
    for (int i = tid; i < 64 * 81; i += 256) rows_[i] = h1tmp[row0 * 81 + i];
    for (int i = tid; i < 6561; i += 256) Wl[i] = Wo1[i];
    __syncthreads();
    float hw = hwp[0];
    float onemhw = 1.0f - hw;
    for (int o = tid; o < 16 * 81; o += 256) {
        int r4 = o / 81, c = o % 81;
        float a0 = 0, a1 = 0, a2 = 0, a3 = 0;
        const float* rp = rows_ + r4 * 4 * 81;
        #pragma unroll 3
        for (int e = 0; e < 81; e++) {
            float w = Wl[e * 81 + c];
            a0 += rp[e] * w; a1 += rp[81 + e] * w;
            a2 += rp[162 + e] * w; a3 += rp[243 + e] * w;
        }
        float av[4] = {a0, a1, a2, a3};
        #pragma unroll
        for (int j = 0; j < 4; j++) {
            int idx = (row0 + r4 * 4 + j) * 81 + c;
            matin[idx] = onemhw * av[j] + hw * h2[idx] + txall[idx];
        }
    }
}

// ---------------- stats: per-channel sum / sumsq via atomics ----------------
__global__ void stats_kernel(const float* __restrict__ in, float* __restrict__ st,
                             int total, int C) {
    __shared__ float ssum[512], ssq[512];
    int tid = threadIdx.x;
    for (int c = tid; c < C; c += blockDim.x) { ssum[c] = 0.0f; ssq[c] = 0.0f; }
    __syncthreads();
    for (int f = blockIdx.x * blockDim.x + tid; f < total; f += gridDim.x * blockDim.x) {
        float v = in[f]; int c = f % C;
        atomicAdd(&ssum[c], v); atomicAdd(&ssq[c], v * v);
    }
    __syncthreads();
    for (int c = tid; c < C; c += blockDim.x) {
        atomicAdd(&st[c], ssum[c]); atomicAdd(&st[C + c], ssq[c]);
    }
}

// ---------------- bn apply (FC head only) ----------------
__global__ void bn_apply_kernel(const float* __restrict__ in, float* __restrict__ out,
                                const float* __restrict__ st, const float* __restrict__ g,
                                const float* __restrict__ bta, int total, int C, float invN) {
    int f = blockIdx.x * blockDim.x + threadIdx.x;
    if (f >= total) return;
    int c = f % C;
    float mean = st[c] * invN;
    float var = st[C + c] * invN - mean * mean;
    out[f] = (in[f] - mean) * rsqrtf(var + EPSV) * g[c] + bta[c];
}

// ---------------- ff1: f1 = relu(bn1(matin) @ ff1_w + b)  (64 rows x 128 cols/block) ----------------
__global__ __launch_bounds__(256) void ff1_kernel(const float* __restrict__ matin,
                           const float* __restrict__ st1, const float* __restrict__ g1,
                           const float* __restrict__ b1, const float* __restrict__ W,
                           const float* __restrict__ bias, float* __restrict__ f1) {
    __shared__ float rows_[64 * 81];
    __shared__ float Wl[81 * 128];
    int row0 = blockIdx.x * 64;
    int c0 = blockIdx.y * 128;
    int tid = threadIdx.x;
    const float invN = 1.0f / 16384.0f;
    for (int i = tid; i < 64 * 81; i += 256) {
        int c = i % 81;
        float mean = st1[c] * invN;
        float var = st1[81 + c] * invN - mean * mean;
        rows_[i] = (matin[row0 * 81 + i] - mean) * rsqrtf(var + EPSV) * g1[c] + b1[c];
    }
    for (int i = tid; i < 81 * 128; i += 256) {
        int e = i >> 7, cc = i & 127;
        Wl[i] = W[e * 256 + c0 + cc];
    }
    __syncthreads();
    for (int o = tid; o < 16 * 128; o += 256) {
        int r4 = o >> 7, cc = o & 127;
        float bv = bias[c0 + cc];
        float a0 = bv, a1 = bv, a2 = bv, a3 = bv;
        const float* rp = rows_ + r4 * 4 * 81;
        #pragma unroll 3
        for (int e = 0; e < 81; e++) {
            float w = Wl[(e << 7) + cc];
            a0 += rp[e] * w; a1 += rp[81 + e] * w;
            a2 += rp[162 + e] * w; a3 += rp[243 + e] * w;
        }
        int base = (row0 + r4 * 4) * 256 + c0 + cc;
        f1[base]       = fmaxf(a0, 0.0f);
        f1[base + 256] = fmaxf(a1, 0.0f);
        f1[base + 512] = fmaxf(a2, 0.0f);
        f1[base + 768] = fmaxf(a3, 0.0f);
    }
}

// ---------------- ff2: t3 = bn1(matin) + relu(bn2(f1) @ ff2_w + b)  (32 rows/block, K split) ----------------
__global__ __launch_bounds__(256) void ff2_kernel(const float* __restrict__ f1,
                           const float* __restrict__ st2, const float* __restrict__ g2,
                           const float* __restrict__ b2, const float* __restrict__ W,
                           const float* __restrict__ bias, const float* __restrict__ matin,
                           const float* __restrict__ st1, const float* __restrict__ g1,
                           const float* __restrict__ b1, float* __restrict__ t3) {
    __shared__ float rows_[32 * 128];
    __shared__ float Wl[128 * 81];
    int row0 = blockIdx.x * 32;
    int tid = threadIdx.x;
    const float invN = 1.0f / 16384.0f;
    float acc[3][4];
    #pragma unroll
    for (int oi = 0; oi < 3; oi++) {
        int o = tid + oi * 256;
        float bv = (o < 648) ? bias[o % 81] : 0.0f;
        #pragma unroll
        for (int j = 0; j < 4; j++) acc[oi][j] = bv;
    }
    for (int half = 0; half < 2; half++) {
        __syncthreads();
        for (int i = tid; i < 32 * 128; i += 256) {
            int c = half * 128 + (i & 127);
            float mean = st2[c] * invN;
            float var = st2[256 + c] * invN - mean * mean;
            rows_[i] = (f1[(row0 + (i >> 7)) * 256 + c] - mean) * rsqrtf(var + EPSV) * g2[c] + b2[c];
        }
        for (int i = tid; i < 128 * 81; i += 256) Wl[i] = W[half * 128 * 81 + i];
        __syncthreads();
        #pragma unroll
        for (int oi = 0; oi < 3; oi++) {
            int o = tid + oi * 256;
            if (o < 648) {
                int r4 = o / 81, c = o % 81;
                const float* rp = rows_ + r4 * 4 * 128;
                #pragma unroll 4
                for (int e = 0; e < 128; e++) {
                    float w = Wl[e * 81 + c];
                    acc[oi][0] += rp[e] * w;       acc[oi][1] += rp[128 + e] * w;
                    acc[oi][2] += rp[256 + e] * w; acc[oi][3] += rp[384 + e] * w;
                }
            }
        }
    }
    #pragma unroll
    for (int oi = 0; oi < 3; oi++) {
        int o = tid + oi * 256;
        if (o < 648) {
            int r4 = o / 81, c = o % 81;
            float mean = st1[c] * invN;
            float var = st1[81 + c] * invN - mean * mean;
            float rstd = rsqrtf(var + EPSV);
            #pragma unroll
            for (int j = 0; j < 4; j++) {
                int idx = (row0 + r4 * 4 + j) * 81 + c;
                float ma = (matin[idx] - mean) * rstd * g1[c] + b1[c];
                t3[idx] = ma + fmaxf(acc[oi][j], 0.0f);
            }
        }
    }
}

// ---------------- token pooling: 32 rows/block, 8 lanes/row ----------------
__global__ __launch_bounds__(256) void token_kernel(const float* __restrict__ t3,
                             const float* __restrict__ st3, const float* __restrict__ g3,
                             const float* __restrict__ b3, const float* __restrict__ tvw,
                             const float* __restrict__ tvb, const float* __restrict__ beta1,
                             const float* __restrict__ basel, const float* __restrict__ a1p,
                             const float* __restrict__ a2p, float* __restrict__ fea) {
    __shared__ float rows_[32 * 81];
    __shared__ float Wu[6561];
    __shared__ float Wv[6561];
    int row0 = blockIdx.x * 32;
    int tid = threadIdx.x;
    const float invN = 1.0f / 16384.0f;
    for (int i = tid; i < 32 * 81; i += 256) {
        int c = i % 81;
        float mean = st3[c] * invN;
        float var = st3[81 + c] * invN - mean * mean;
        rows_[i] = (t3[row0 * 81 + i] - mean) * rsqrtf(var + EPSV) * g3[c] + b3[c];
    }
    for (int i = tid; i < 6561; i += 256) { Wu[i] = tvw[i]; Wv[i] = beta1[i]; }
    __syncthreads();
    int r = tid >> 3, j = tid & 7;
    const float* rp = rows_ + r * 81;
    float u[11], v[11];
    #pragma unroll
    for (int dd = 0; dd < 11; dd++) {
        int d = j + dd * 8;
        u[dd] = (d < 81) ? tvb[d] : 0.0f;
        v[dd] = (d < 81) ? 0.0f : -1e30f;
    }
    for (int e = 0; e < 81; e++) {
        float rv = rp[e];
        #pragma unroll
        for (int dd = 0; dd < 11; dd++) {
            int d = j + dd * 8;
            if (d < 81) {
                u[dd] += rv * Wu[e * 81 + d];
                v[dd] += rv * Wv[e * 81 + d];
            }
        }
    }
    float mx = -1e30f;
    #pragma unroll
    for (int dd = 0; dd < 11; dd++) mx = fmaxf(mx, v[dd]);
    #pragma unroll
    for (int msk = 1; msk < 8; msk <<= 1) mx = fmaxf(mx, __shfl_xor(mx, msk, 8));
    float sp = 0.0f, sup = 0.0f;
    #pragma unroll
    for (int dd = 0; dd < 11; dd++) {
        float p = __expf(v[dd] - mx);
        sp += p; sup += u[dd] * p;
    }
    #pragma unroll
    for (int msk = 1; msk < 8; msk <<= 1) {
        sp  += __shfl_xor(sp, msk, 8);
        sup += __shfl_xor(sup, msk, 8);
    }
    if (j == 0) {
        int rg = row0 + r;
        int b = rg >> 9, s = rg & 511;
        fea[rg] = a1p[0] * (sup / sp) + a2p[0] * basel[b * 2048 + s * 4];
    }
}

// ---------------- small FC: out = act(in @ W + b) ; in (32,K) ----------------
__global__ void fc_kernel(const float* __restrict__ in, const float* __restrict__ W,
                          const float* __restrict__ bias, float* __restrict__ out,
                          int K, int N, int mode) {
    int idx = blockIdx.x * blockDim.x + threadIdx.x;
    if (idx >= 32 * N) return;
    int b = idx / N, j = idx % N;
    float acc = bias[j];
    const float* ip = in + b * K;
    #pragma unroll 8
    for (int k = 0; k < K; k++) acc += ip[k] * W[k * N + j];
    if (mode == 1) acc = fmaxf(acc, 0.0f);
    else if (mode == 2) acc = tanhf(acc);
    out[idx] = acc;
}

// =======================================================================
extern "C" void kernel_launch(void* const* d_in, const int* in_sizes, int n_in,
                              void* d_out, int out_size, void* d_ws, size_t ws_size,
                              hipStream_t stream) {
    const float* x       = (const float*)d_in[0];
    const float* basel   = (const float*)d_in[1];
    const float* cali    = (const float*)d_in[2];
    const float* Wq      = (const float*)d_in[3];
    const float* Wk      = (const float*)d_in[4];
    const float* Wq2     = (const float*)d_in[5];
    const float* Wk2     = (const float*)d_in[6];
    const float* Wv2     = (const float*)d_in[7];
    const float* Cv      = (const float*)d_in[8];
    const float* Wo1     = (const float*)d_in[9];
    const float* Wo2     = (const float*)d_in[10];
    const float* corr_w  = (const float*)d_in[11];
    const float* h_w     = (const float*)d_in[12];
    const float* corr    = (const float*)d_in[13];
    const float* g1      = (const float*)d_in[14];
    const float* b1      = (const float*)d_in[15];
    const float* ff1_w   = (const float*)d_in[16];
    const float* ff1_b   = (const float*)d_in[17];
    const float* g2      = (const float*)d_in[18];
    const float* b2      = (const float*)d_in[19];
    const float* ff2_w   = (const float*)d_in[20];
    const float* ff2_b   = (const float*)d_in[21];
    const float* g3      = (const float*)d_in[22];
    const float* b3      = (const float*)d_in[23];
    const float* tvw     = (const float*)d_in[24];
    const float* tvb     = (const float*)d_in[25];
    const float* beta1   = (const float*)d_in[26];
    const float* a1      = (const float*)d_in[27];
    const float* a2      = (const float*)d_in[28];
    const float* fc1_w   = (const float*)d_in[29];
    const float* fc1_b   = (const float*)d_in[30];
    const float* bnf1_g  = (const float*)d_in[31];
    const float* bnf1_b  = (const float*)d_in[32];
    const float* fc2_w   = (const float*)d_in[33];
    const float* fc2_b   = (const float*)d_in[34];
    const float* bnf2_g  = (const float*)d_in[35];
    const float* bnf2_b  = (const float*)d_in[36];
    const float* fc3_w   = (const float*)d_in[37];
    const float* fc3_b   = (const float*)d_in[38];
    float* out = (float*)d_out;
    float* ws = (float*)d_ws;

    // ---- workspace layout (float offsets) ----
    const size_t SCAL  = 0;         // 2
    const size_t PART  = 16;        // 128
    const size_t ST1   = 512;       // 162
    const size_t ST2   = 768;       // 512
    const size_t ST3   = 1536;      // 162
    const size_t ST4   = 1792;      // 1024
    const size_t ST5   = 2880;      // 512
    const size_t FEA   = 4096;      // 16384
    const size_t FCH1  = 20480;     // 16384
    const size_t FCH2  = 36864;     // 8192
    const size_t PEO   = 45056;     // 41472
    const size_t TX    = 90112;     // 1990656
    const size_t Q2O   = 2080768;   // 1327104   (reused: h1tmp)
    const size_t KCO   = 3407872;   // 1990656   (reused: Qs)
    const size_t VCO   = 5398528;   // 1990656   (reused: Ks)
    const size_t TMP2  = 7389184;   // 1327104   (reused: matin)
    const size_t H2O   = 8716288;   // 1327104   (reused: t3)
    const size_t XHO   = 10043392;  // 1327104
    const size_t BIASO = 11370496;  // 262144
    const size_t F1O   = 11632640;  // 4194304
    // total ~15.83M floats = 63.3 MB

    float* scal  = ws + SCAL;
    float* part  = ws + PART;
    float* st1   = ws + ST1;
    float* st2   = ws + ST2;
    float* st3   = ws + ST3;
    float* st4   = ws + ST4;
    float* st5   = ws + ST5;
    float* fea   = ws + FEA;
    float* fch1  = ws + FCH1;
    float* fch2  = ws + FCH2;
    float* pe    = ws + PEO;
    float* txall = ws + TX;
    float* Q2    = ws + Q2O;
    float* Kc    = ws + KCO;
    float* Vc    = ws + VCO;
    float* tmp2  = ws + TMP2;
    float* h2    = ws + H2O;
    float* xh    = ws + XHO;
    float* biasT = ws + BIASO;
    float* f1    = ws + F1O;
    float* h1tmp = Q2;     // reuse
    float* Qs    = Kc;     // reuse
    float* Ks    = Vc;     // reuse
    float* matin = tmp2;   // reuse
    float* t3    = h2;     // reuse

    // zero scal/part/stats region — capture-safe
    hipMemsetAsync(ws, 0, 4096 * sizeof(float), stream);

    minmax_part<<<64, 256, 0, stream>>>(x, part);
    minmax_fin<<<1, 64, 0, stream>>>(part, scal);

    pe_kernel<<<(512 * 81 + 255) / 256, 256, 0, stream>>>(pe);

    tokenize_kernel<<<(48 * 512 * 81 + 255) / 256, 256, 0, stream>>>(x, cali, scal, pe, txall);

    qkv2_kernel<<<384, 256, 0, stream>>>(txall, Wq2, Wk2, Wv2, Q2, Kc, Vc);

    attn2_kernel<<<(512 * 9 * 32) / 256, 256, 0, stream>>>(Q2, Kc, Vc, tmp2);

    h2xh_kernel<<<256, 256, 0, stream>>>(tmp2, Wo2, txall, h2, xh);

    qks_kernel<<<256, 256, 0, stream>>>(xh, Wq, Wk, Qs, Ks);

    biasmm_kernel<<<dim3(16, 16), dim3(16, 16), 0, stream>>>(corr, Cv, biasT);

    attn1_kernel<<<288, 512, 0, stream>>>(Qs, Ks, biasT, corr_w, h1tmp);

    h1o_kernel<<<256, 256, 0, stream>>>(h1tmp, Wo1, h2, txall, h_w, matin);

    stats_kernel<<<256, 256, 0, stream>>>(matin, st1, 16384 * 81, 81);

    ff1_kernel<<<dim3(256, 2), 256, 0, stream>>>(matin, st1, g1, b1, ff1_w, ff1_b, f1);

    stats_kernel<<<256, 256, 0, stream>>>(f1, st2, 16384 * 256, 256);

    ff2_kernel<<<512, 256, 0, stream>>>(f1, st2, g2, b2, ff2_w, ff2_b,
                                        matin, st1, g1, b1, t3);

    stats_kernel<<<256, 256, 0, stream>>>(t3, st3, 16384 * 81, 81);

    token_kernel<<<512, 256, 0, stream>>>(t3, st3, g3, b3, tvw, tvb, beta1, basel, a1, a2, fea);

    // FC head
    fc_kernel<<<(32 * 512 + 255) / 256, 256, 0, stream>>>(fea, fc1_w, fc1_b, fch1, 512, 512, 1);
    stats_kernel<<<32, 256, 0, stream>>>(fch1, st4, 32 * 512, 512);
    bn_apply_kernel<<<(32 * 512 + 255) / 256, 256, 0, stream>>>(fch1, fch1, st4, bnf1_g, bnf1_b,
                                                                32 * 512, 512, 1.0f / 32.0f);

    fc_kernel<<<(32 * 256 + 255) / 256, 256, 0, stream>>>(fch1, fc2_w, fc2_b, fch2, 512, 256, 1);
    stats_kernel<<<16, 256, 0, stream>>>(fch2, st5, 32 * 256, 256);
    bn_apply_kernel<<<(32 * 256 + 255) / 256, 256, 0, stream>>>(fch2, fch2, st5, bnf2_g, bnf2_b,
                                                                32 * 256, 256, 1.0f / 32.0f);

    fc_kernel<<<1, 128, 0, stream>>>(fch2, fc3_w, fc3_b, out, 256, 4, 2);
}

// Round 3
// 535.559 us; speedup vs baseline: 2.4108x; 1.2255x over previous
//
#include <hip/hip_runtime.h>
#include <hip/hip_bf16.h>
#include <math.h>

#define EPSV 1e-5f

// ---------------- sizes ----------------
// B=32 Bc=16 L=2048 TOKEN=40 STRIDE=4 D=81 H=9 dk=9 S=512 FF=256 FC1=512 FC2=256 Y=4

// ---------------- minmax: two-stage ----------------
__global__ void minmax_part(const float* __restrict__ x, float* __restrict__ part) {
    __shared__ float smin[256], smax[256];
    int tid = threadIdx.x;
    float mn = 1e30f, mx = -1e30f;
    for (int i = blockIdx.x * 256 + tid; i < 32 * 2008; i += 64 * 256) {
        int b = i / 2008, c = i % 2008 + 20;
        float v = x[b * 2048 + c];
        mn = fminf(mn, v); mx = fmaxf(mx, v);
    }
    smin[tid] = mn; smax[tid] = mx; __syncthreads();
    for (int off = 128; off > 0; off >>= 1) {
        if (tid < off) { smin[tid] = fminf(smin[tid], smin[tid + off]); smax[tid] = fmaxf(smax[tid], smax[tid + off]); }
        __syncthreads();
    }
    if (tid == 0) { part[blockIdx.x] = smin[0]; part[64 + blockIdx.x] = smax[0]; }
}

__global__ void minmax_fin(const float* __restrict__ part, float* __restrict__ scal) {
    __shared__ float smn[64], smx[64];
    int tid = threadIdx.x;
    smn[tid] = part[tid]; smx[tid] = part[64 + tid]; __syncthreads();
    for (int off = 32; off > 0; off >>= 1) {
        if (tid < off) { smn[tid] = fminf(smn[tid], smn[tid + off]); smx[tid] = fmaxf(smx[tid], smx[tid + off]); }
        __syncthreads();
    }
    if (tid == 0) { scal[0] = smn[0]; scal[1] = smx[0] - smn[0]; }
}

// ---------------- PE table (512 x 81) ----------------
__global__ void pe_kernel(float* __restrict__ pe) {
    int idx = blockIdx.x * blockDim.x + threadIdx.x;
    if (idx >= 512 * 81) return;
    int d = idx % 81, s = idx / 81;
    int j = d >> 1;
    float dv = __expf(-9.210340371976184f * (2.0f * (float)j) / 81.0f);
    float ang = (float)s * dv;
    pe[idx] = (d & 1) ? cosf(ang) : sinf(ang);
}

// ---------------- tokenize + add PE ----------------
__global__ void tokenize_kernel(const float* __restrict__ x, const float* __restrict__ cali,
                                const float* __restrict__ scal, const float* __restrict__ pe,
                                float* __restrict__ txall) {
    int idx = blockIdx.x * blockDim.x + threadIdx.x;
    if (idx >= 48 * 512 * 81) return;
    int d = idx % 81;
    int s = (idx / 81) % 512;
    int r = idx / (81 * 512);
    float xm = scal[0], inv_xs = 1.0f / scal[1];
    int oc = s * 4 + d - 40;
    float val = 0.0f;
    if (oc >= 0 && oc < 2048) {
        float sv = (r < 32) ? x[r * 2048 + oc] : cali[(r - 32) * 2048 + oc];
        val = (sv - xm) * inv_xs;
    }
    txall[idx] = val + pe[s * 81 + d];
}

// ---------------- qkv2: 64 rows/block, W in LDS, 4-row reg tile ----------------
__global__ __launch_bounds__(256) void qkv2_kernel(const float* __restrict__ txall,
                            const float* __restrict__ Wq2, const float* __restrict__ Wk2,
                            const float* __restrict__ Wv2,
                            float* __restrict__ Q2, float* __restrict__ Kc, float* __restrict__ Vc) {
    __shared__ float rows_[64 * 81];
    __shared__ float Wl[6561];
    int blk = blockIdx.x;            // 0..383
    int row0 = blk * 64;             // k*512+s flattened
    int k = row0 >> 9;               // block-uniform
    int s0 = row0 & 511;
    int tid = threadIdx.x;
    for (int i = tid; i < 64 * 81; i += 256) rows_[i] = txall[row0 * 81 + i];
    for (int t = 0; t < 3; t++) {
        if (t == 0 && k >= 32) continue;   // block-uniform
        const float* W = (t == 0) ? Wq2 : (t == 1) ? Wk2 : Wv2;
        __syncthreads();
        for (int i = tid; i < 6561; i += 256) {
            int e = i / 81, hd = i % 81, h = hd / 9, d = hd % 9;
            Wl[i] = W[h * 729 + e * 9 + d];     // Wl[e*81+hd]
        }
        __syncthreads();
        for (int o = tid; o < 16 * 81; o += 256) {
            int r4 = o / 81, hd = o % 81;
            float a0 = 0, a1 = 0, a2 = 0, a3 = 0;
            const float* rp = rows_ + r4 * 4 * 81;
            #pragma unroll 3
            for (int e = 0; e < 81; e++) {
                float w = Wl[e * 81 + hd];
                a0 += rp[e] * w; a1 += rp[81 + e] * w;
                a2 += rp[162 + e] * w; a3 += rp[243 + e] * w;
            }
            int h = hd / 9, d = hd % 9;
            int sb = s0 + r4 * 4;
            float av[4] = {a0, a1, a2, a3};
            #pragma unroll
            for (int j = 0; j < 4; j++) {
                int s = sb + j;
                if (t == 0)      Q2[((s * 9 + h) * 32 + k) * 9 + d] = av[j];
                else if (t == 1) Kc[((s * 9 + h) * 48 + k) * 9 + d] = av[j];
                else             Vc[((s * 9 + h) * 48 + k) * 9 + d] = av[j];
            }
        }
    }
}

// ---------------- attention-2 (masked: key==b or key>=32) ----------------
__global__ void attn2_kernel(const float* __restrict__ Q2, const float* __restrict__ Kc,
                             const float* __restrict__ Vc, float* __restrict__ tmp2) {
    int tid = blockIdx.x * blockDim.x + threadIdx.x;
    if (tid >= 512 * 9 * 32) return;
    int b = tid & 31;
    int h = (tid >> 5) % 9;
    int s = tid / 288;
    const float* q = Q2 + ((s * 9 + h) * 32 + b) * 9;
    float qr[9];
    #pragma unroll
    for (int d = 0; d < 9; d++) qr[d] = q[d];
    const float* Kb = Kc + (s * 9 + h) * 48 * 9;
    const float* Vb = Vc + (s * 9 + h) * 48 * 9;
    float sc[17];
    float m = -1e30f;
    const float inv3 = 1.0f / 3.0f;
    #pragma unroll
    for (int j = 0; j < 17; j++) {
        int k = (j == 0) ? b : 31 + j;
        const float* kp = Kb + k * 9;
        float acc = 0.0f;
        #pragma unroll
        for (int d = 0; d < 9; d++) acc += qr[d] * kp[d];
        acc *= inv3;
        sc[j] = acc; m = fmaxf(m, acc);
    }
    float l = 0.0f, outv[9];
    #pragma unroll
    for (int d = 0; d < 9; d++) outv[d] = 0.0f;
    #pragma unroll
    for (int j = 0; j < 17; j++) {
        float p = __expf(sc[j] - m); l += p;
        int k = (j == 0) ? b : 31 + j;
        const float* vp = Vb + k * 9;
        #pragma unroll
        for (int d = 0; d < 9; d++) outv[d] += p * vp[d];
    }
    float invl = 1.0f / l;
    float* op = tmp2 + (b * 512 + s) * 81 + h * 9;
    #pragma unroll
    for (int d = 0; d < 9; d++) op[d] = outv[d] * invl;
}

// ---------------- h2 = tmp2 @ Wo2 ; xh = tx + h2  (64 rows/block) ----------------
__global__ __launch_bounds__(256) void h2xh_kernel(const float* __restrict__ tmp2,
                            const float* __restrict__ Wo2, const float* __restrict__ txall,
                            float* __restrict__ h2, float* __restrict__ xh) {
    __shared__ float rows_[64 * 81];
    __shared__ float Wl[6561];
    int row0 = blockIdx.x * 64;
    int tid = threadIdx.x;
    for (int i = tid; i < 64 * 81; i += 256) rows_[i] = tmp2[row0 * 81 + i];
    for (int i = tid; i < 6561; i += 256) Wl[i] = Wo2[i];
    __syncthreads();
    for (int o = tid; o < 16 * 81; o += 256) {
        int r4 = o / 81, c = o % 81;
        float a0 = 0, a1 = 0, a2 = 0, a3 = 0;
        const float* rp = rows_ + r4 * 4 * 81;
        #pragma unroll 3
        for (int e = 0; e < 81; e++) {
            float w = Wl[e * 81 + c];
            a0 += rp[e] * w; a1 += rp[81 + e] * w;
            a2 += rp[162 + e] * w; a3 += rp[243 + e] * w;
        }
        float av[4] = {a0, a1, a2, a3};
        #pragma unroll
        for (int j = 0; j < 4; j++) {
            int idx = (row0 + r4 * 4 + j) * 81 + c;
            h2[idx] = av[j];
            xh[idx] = txall[idx] + av[j];
        }
    }
}

// ---------------- Qs/Ks projections (Vs == Qs) ----------------
__global__ __launch_bounds__(256) void qks_kernel(const float* __restrict__ xh,
                           const float* __restrict__ Wq, const float* __restrict__ Wk,
                           float* __restrict__ Qs, float* __restrict__ Ks) {
    __shared__ float rows_[64 * 81];
    __shared__ float Wl[6561];
    int blk = blockIdx.x;            // 0..255
    int row0 = blk * 64;             // b*512+s
    int b = row0 >> 9;
    int s0 = row0 & 511;
    int tid = threadIdx.x;
    for (int i = tid; i < 64 * 81; i += 256) rows_[i] = xh[row0 * 81 + i];
    for (int t = 0; t < 2; t++) {
        const float* W = (t == 0) ? Wq : Wk;
        __syncthreads();
        for (int i = tid; i < 6561; i += 256) {
            int e = i / 81, hd = i % 81, h = hd / 9, d = hd % 9;
            Wl[i] = W[h * 729 + e * 9 + d];
        }
        __syncthreads();
        float* dst = (t == 0) ? Qs : Ks;
        for (int o = tid; o < 16 * 81; o += 256) {
            int r4 = o / 81, hd = o % 81;
            float a0 = 0, a1 = 0, a2 = 0, a3 = 0;
            const float* rp = rows_ + r4 * 4 * 81;
            #pragma unroll 3
            for (int e = 0; e < 81; e++) {
                float w = Wl[e * 81 + hd];
                a0 += rp[e] * w; a1 += rp[81 + e] * w;
                a2 += rp[162 + e] * w; a3 += rp[243 + e] * w;
            }
            int h = hd / 9, d = hd % 9;
            int sb = s0 + r4 * 4;
            float av[4] = {a0, a1, a2, a3};
            #pragma unroll
            for (int j = 0; j < 4; j++)
                dst[((b * 9 + h) * 512 + (sb + j)) * 9 + d] = av[j];
        }
    }
}

// ---------------- biasT = (corr @ Cv)^T / sqrt(S) ----------------
__global__ __launch_bounds__(256) void biasmm_kernel(const float* __restrict__ corr,
                              const float* __restrict__ Cv, float* __restrict__ biasT) {
    __shared__ float As[32][33];
    __shared__ float Bs[32][33];
    int tx = threadIdx.x, ty = threadIdx.y;   // 16 x 16
    int tid = ty * 16 + tx;
    int t0 = blockIdx.y * 32, s0 = blockIdx.x * 32;
    float a00 = 0, a01 = 0, a10 = 0, a11 = 0;
    for (int k0 = 0; k0 < 512; k0 += 32) {
        for (int ii = tid; ii < 1024; ii += 256) {
            int r = ii >> 5, c = ii & 31;
            As[r][c] = Cv[(k0 + r) * 512 + t0 + c];
            Bs[r][c] = corr[(s0 + r) * 512 + k0 + c];
        }
        __syncthreads();
        #pragma unroll
        for (int kk = 0; kk < 32; kk++) {
            float b0 = Bs[tx][kk], b1 = Bs[tx + 16][kk];
            float c0 = As[kk][ty], c1 = As[kk][ty + 16];
            a00 += c0 * b0; a01 += c0 * b1; a10 += c1 * b0; a11 += c1 * b1;
        }
        __syncthreads();
    }
    const float invs = 0.04419417382415922f;   // 1/sqrt(512)
    biasT[(t0 + ty) * 512 + s0 + tx]            = a00 * invs;
    biasT[(t0 + ty) * 512 + s0 + tx + 16]       = a01 * invs;
    biasT[(t0 + ty + 16) * 512 + s0 + tx]       = a10 * invs;
    biasT[(t0 + ty + 16) * 512 + s0 + tx + 16]  = a11 * invs;
}

// ---------------- attention-1: 2 blocks per (b,h), 16-key chunks, b128 LDS reads ----------------
__global__ __launch_bounds__(256) void attn1_kernel(const float* __restrict__ Qs,
                                                    const float* __restrict__ Ks,
                                                    const float* __restrict__ biasT,
                                                    const float* __restrict__ cwp,
                                                    float* __restrict__ h1tmp) {
    int blk = blockIdx.x;          // 0..575
    int bh = blk >> 1;             // b*9+h
    int half = blk & 1;
    int b = bh / 9, h = bh % 9;
    __shared__ float Ksh[512][12];   // 9 used, pad to 12 for 16B-aligned b128 reads
    __shared__ float Vsh[512][12];
    int tid = threadIdx.x;
    const float* Kb = Ks + bh * 4608;
    const float* Qb = Qs + bh * 4608;
    for (int i = tid; i < 4608; i += 256) {
        int r = i / 9, c = i % 9;
        Ksh[r][c] = Kb[i];
        Vsh[r][c] = Qb[i];   // Vs == Qs
    }
    __syncthreads();
    int q = half * 256 + tid;
    float qv[9];
    #pragma unroll
    for (int d = 0; d < 9; d++) qv[d] = Vsh[q][d];
    float cw = cwp[0];
    float c1 = (1.0f - cw) / 3.0f;
    float m = -1e30f, l = 0.0f;
    float acc[9];
    #pragma unroll
    for (int d = 0; d < 9; d++) acc[d] = 0.0f;
    const float* bp = biasT + q;
    for (int t0 = 0; t0 < 512; t0 += 16) {
        float sc[16];
        #pragma unroll
        for (int tt = 0; tt < 16; tt++) {
            const float4* kp = reinterpret_cast<const float4*>(Ksh[t0 + tt]);
            float4 k0 = kp[0], k1 = kp[1], k2 = kp[2];
            float s = qv[0] * k0.x + qv[1] * k0.y + qv[2] * k0.z + qv[3] * k0.w
                    + qv[4] * k1.x + qv[5] * k1.y + qv[6] * k1.z + qv[7] * k1.w
                    + qv[8] * k2.x;
            sc[tt] = c1 * s + cw * bp[(t0 + tt) << 9];
        }
        float cm = sc[0];
        #pragma unroll
        for (int tt = 1; tt < 16; tt++) cm = fmaxf(cm, sc[tt]);
        float nm = fmaxf(m, cm);
        float f = __expf(m - nm);
        m = nm;
        l *= f;
        #pragma unroll
        for (int d = 0; d < 9; d++) acc[d] *= f;
        #pragma unroll
        for (int tt = 0; tt < 16; tt++) {
            float p = __expf(sc[tt] - nm);
            l += p;
            const float4* vp = reinterpret_cast<const float4*>(Vsh[t0 + tt]);
            float4 v0 = vp[0], v1 = vp[1], v2 = vp[2];
            acc[0] += p * v0.x; acc[1] += p * v0.y; acc[2] += p * v0.z; acc[3] += p * v0.w;
            acc[4] += p * v1.x; acc[5] += p * v1.y; acc[6] += p * v1.z; acc[7] += p * v1.w;
            acc[8] += p * v2.x;
        }
    }
    float invl = 1.0f / l;
    float* op = h1tmp + (b * 512 + q) * 81 + h * 9;
    #pragma unroll
    for (int d = 0; d < 9; d++) op[d] = acc[d] * invl;
}

// ---------------- matin = (1-hw)*(h1tmp@Wo1) + hw*h2 + tx ; fused st1 partials ----------------
__global__ __launch_bounds__(256) void h1o_kernel(const float* __restrict__ h1tmp,
                           const float* __restrict__ Wo1, const float* __restrict__ h2,
                           const float* __restrict__ txall, const float* __restrict__ hwp,
                           float* __restrict__ matin, float* __restrict__ st1) {
    __shared__ float rows_[64 * 81];
    __shared__ float Wl[6561];
    __shared__ float ssum[81], ssq[81];
    int row0 = blockIdx.x * 64;
    int tid = threadIdx.x;
    if (tid < 81) { ssum[tid] = 0.0f; ssq[tid] = 0.0f; }
    for (int i = tid; i < 64 * 81; i += 256) rows_[i] = h1tmp[row0 * 81 + i];
    for (int i = tid; i < 6561; i += 256) Wl[i] = Wo1[i];
    __syncthreads();
    float hw = hwp[0];
    float onemhw = 1.0f - hw;
    for (int o = tid; o < 16 * 81; o += 256) {
        int r4 = o / 81, c = o % 81;
        float a0 = 0, a1 = 0, a2 = 0, a3 = 0;
        const float* rp = rows_ + r4 * 4 * 81;
        #pragma unroll 3
        for (int e = 0; e < 81; e++) {
            float w = Wl[e * 81 + c];
            a0 += rp[e] * w; a1 += rp[81 + e] * w;
            a2 += rp[162 + e] * w; a3 += rp[243 + e] * w;
        }
        float av[4] = {a0, a1, a2, a3};
        float ls = 0.0f, lq = 0.0f;
        #pragma unroll
        for (int j = 0; j < 4; j++) {
            int idx = (row0 + r4 * 4 + j) * 81 + c;
            float v = onemhw * av[j] + hw * h2[idx] + txall[idx];
            matin[idx] = v;
            ls += v; lq += v * v;
        }
        atomicAdd(&ssum[c], ls);
        atomicAdd(&ssq[c], lq);
    }
    __syncthreads();
    if (tid < 81) {
        atomicAdd(&st1[tid], ssum[tid]);
        atomicAdd(&st1[81 + tid], ssq[tid]);
    }
}

// ---------------- ff1: f1 = relu(bn1(matin) @ ff1_w + b) ; fused st2 partials ----------------
__global__ __launch_bounds__(256) void ff1_kernel(const float* __restrict__ matin,
                           const float* __restrict__ st1, const float* __restrict__ g1,
                           const float* __restrict__ b1, const float* __restrict__ W,
                           const float* __restrict__ bias, float* __restrict__ f1,
                           float* __restrict__ st2) {
    __shared__ float rows_[64 * 81];
    __shared__ float Wl[81 * 128];
    __shared__ float s2s[128], s2q[128];
    int row0 = blockIdx.x * 64;
    int c0 = blockIdx.y * 128;
    int tid = threadIdx.x;
    const float invN = 1.0f / 16384.0f;
    if (tid < 128) { s2s[tid] = 0.0f; s2q[tid] = 0.0f; }
    for (int i = tid; i < 64 * 81; i += 256) {
        int c = i % 81;
        float mean = st1[c] * invN;
        float var = st1[81 + c] * invN - mean * mean;
        rows_[i] = (matin[row0 * 81 + i] - mean) * rsqrtf(var + EPSV) * g1[c] + b1[c];
    }
    for (int i = tid; i < 81 * 128; i += 256) {
        int e = i >> 7, cc = i & 127;
        Wl[i] = W[e * 256 + c0 + cc];
    }
    __syncthreads();
    for (int o = tid; o < 16 * 128; o += 256) {
        int r4 = o >> 7, cc = o & 127;
        float bv = bias[c0 + cc];
        float a0 = bv, a1 = bv, a2 = bv, a3 = bv;
        const float* rp = rows_ + r4 * 4 * 81;
        #pragma unroll 3
        for (int e = 0; e < 81; e++) {
            float w = Wl[(e << 7) + cc];
            a0 += rp[e] * w; a1 += rp[81 + e] * w;
            a2 += rp[162 + e] * w; a3 += rp[243 + e] * w;
        }
        a0 = fmaxf(a0, 0.0f); a1 = fmaxf(a1, 0.0f);
        a2 = fmaxf(a2, 0.0f); a3 = fmaxf(a3, 0.0f);
        int base = (row0 + r4 * 4) * 256 + c0 + cc;
        f1[base]       = a0;
        f1[base + 256] = a1;
        f1[base + 512] = a2;
        f1[base + 768] = a3;
        atomicAdd(&s2s[cc], a0 + a1 + a2 + a3);
        atomicAdd(&s2q[cc], a0 * a0 + a1 * a1 + a2 * a2 + a3 * a3);
    }
    __syncthreads();
    if (tid < 128) {
        atomicAdd(&st2[c0 + tid], s2s[tid]);
        atomicAdd(&st2[256 + c0 + tid], s2q[tid]);
    }
}

// ---------------- ff2: t3 = bn1(matin) + relu(bn2(f1) @ ff2_w + b) ; fused st3 ----------------
__global__ __launch_bounds__(256) void ff2_kernel(const float* __restrict__ f1,
                           const float* __restrict__ st2, const float* __restrict__ g2,
                           const float* __restrict__ b2, const float* __restrict__ W,
                           const float* __restrict__ bias, const float* __restrict__ matin,
                           const float* __restrict__ st1, const float* __restrict__ g1,
                           const float* __restrict__ b1, float* __restrict__ t3,
                           float* __restrict__ st3) {
    __shared__ float rows_[32 * 128];
    __shared__ float Wl[128 * 81];
    __shared__ float s3s[81], s3q[81];
    int row0 = blockIdx.x * 32;
    int tid = threadIdx.x;
    const float invN = 1.0f / 16384.0f;
    if (tid < 81) { s3s[tid] = 0.0f; s3q[tid] = 0.0f; }
    float acc[3][4];
    #pragma unroll
    for (int oi = 0; oi < 3; oi++) {
        int o = tid + oi * 256;
        float bv = (o < 648) ? bias[o % 81] : 0.0f;
        #pragma unroll
        for (int j = 0; j < 4; j++) acc[oi][j] = bv;
    }
    for (int half = 0; half < 2; half++) {
        __syncthreads();
        for (int i = tid; i < 32 * 128; i += 256) {
            int c = half * 128 + (i & 127);
            float mean = st2[c] * invN;
            float var = st2[256 + c] * invN - mean * mean;
            rows_[i] = (f1[(row0 + (i >> 7)) * 256 + c] - mean) * rsqrtf(var + EPSV) * g2[c] + b2[c];
        }
        for (int i = tid; i < 128 * 81; i += 256) Wl[i] = W[half * 128 * 81 + i];
        __syncthreads();
        #pragma unroll
        for (int oi = 0; oi < 3; oi++) {
            int o = tid + oi * 256;
            if (o < 648) {
                int r4 = o / 81, c = o % 81;
                const float* rp = rows_ + r4 * 4 * 128;
                #pragma unroll 4
                for (int e = 0; e < 128; e++) {
                    float w = Wl[e * 81 + c];
                    acc[oi][0] += rp[e] * w;       acc[oi][1] += rp[128 + e] * w;
                    acc[oi][2] += rp[256 + e] * w; acc[oi][3] += rp[384 + e] * w;
                }
            }
        }
    }
    #pragma unroll
    for (int oi = 0; oi < 3; oi++) {
        int o = tid + oi * 256;
        if (o < 648) {
            int r4 = o / 81, c = o % 81;
            float mean = st1[c] * invN;
            float var = st1[81 + c] * invN - mean * mean;
            float rstd = rsqrtf(var + EPSV);
            float ls = 0.0f, lq = 0.0f;
            #pragma unroll
            for (int j = 0; j < 4; j++) {
                int idx = (row0 + r4 * 4 + j) * 81 + c;
                float ma = (matin[idx] - mean) * rstd * g1[c] + b1[c];
                float v = ma + fmaxf(acc[oi][j], 0.0f);
                t3[idx] = v;
                ls += v; lq += v * v;
            }
            atomicAdd(&s3s[c], ls);
            atomicAdd(&s3q[c], lq);
        }
    }
    __syncthreads();
    if (tid < 81) {
        atomicAdd(&st3[tid], s3s[tid]);
        atomicAdd(&st3[81 + tid], s3q[tid]);
    }
}

// ---------------- token pooling: 32 rows/block, 8 lanes/row ----------------
__global__ __launch_bounds__(256) void token_kernel(const float* __restrict__ t3,
                             const float* __restrict__ st3, const float* __restrict__ g3,
                             const float* __restrict__ b3, const float* __restrict__ tvw,
                             const float* __restrict__ tvb, const float* __restrict__ beta1,
                             const float* __restrict__ basel, const float* __restrict__ a1p,
                             const float* __restrict__ a2p, float* __restrict__ fea) {
    __shared__ float rows_[32 * 81];
    __shared__ float Wu[6561];
    __shared__ float Wv[6561];
    int row0 = blockIdx.x * 32;
    int tid = threadIdx.x;
    const float invN = 1.0f / 16384.0f;
    for (int i = tid; i < 32 * 81; i += 256) {
        int c = i % 81;
        float mean = st3[c] * invN;
        float var = st3[81 + c] * invN - mean * mean;
        rows_[i] = (t3[row0 * 81 + i] - mean) * rsqrtf(var + EPSV) * g3[c] + b3[c];
    }
    for (int i = tid; i < 6561; i += 256) { Wu[i] = tvw[i]; Wv[i] = beta1[i]; }
    __syncthreads();
    int r = tid >> 3, j = tid & 7;
    const float* rp = rows_ + r * 81;
    float u[11], v[11];
    #pragma unroll
    for (int dd = 0; dd < 11; dd++) {
        int d = j + dd * 8;
        u[dd] = (d < 81) ? tvb[d] : 0.0f;
        v[dd] = (d < 81) ? 0.0f : -1e30f;
    }
    for (int e = 0; e < 81; e++) {
        float rv = rp[e];
        #pragma unroll
        for (int dd = 0; dd < 11; dd++) {
            int d = j + dd * 8;
            if (d < 81) {
                u[dd] += rv * Wu[e * 81 + d];
                v[dd] += rv * Wv[e * 81 + d];
            }
        }
    }
    float mx = -1e30f;
    #pragma unroll
    for (int dd = 0; dd < 11; dd++) mx = fmaxf(mx, v[dd]);
    #pragma unroll
    for (int msk = 1; msk < 8; msk <<= 1) mx = fmaxf(mx, __shfl_xor(mx, msk, 8));
    float sp = 0.0f, sup = 0.0f;
    #pragma unroll
    for (int dd = 0; dd < 11; dd++) {
        float p = __expf(v[dd] - mx);
        sp += p; sup += u[dd] * p;
    }
    #pragma unroll
    for (int msk = 1; msk < 8; msk <<= 1) {
        sp  += __shfl_xor(sp, msk, 8);
        sup += __shfl_xor(sup, msk, 8);
    }
    if (j == 0) {
        int rg = row0 + r;
        int b = rg >> 9, s = rg & 511;
        fea[rg] = a1p[0] * (sup / sp) + a2p[0] * basel[b * 2048 + s * 4];
    }
}

// ---------------- fc1: relu(fea @ W + b), fused st4 ----------------
__global__ void fc1_kernel(const float* __restrict__ in, const float* __restrict__ W,
                           const float* __restrict__ bias, float* __restrict__ out,
                           float* __restrict__ st) {
    int idx = blockIdx.x * blockDim.x + threadIdx.x;
    if (idx >= 32 * 512) return;
    int b = idx >> 9, j = idx & 511;
    float acc = bias[j];
    const float* ip = in + (b << 9);
    #pragma unroll 8
    for (int k = 0; k < 512; k++) acc += ip[k] * W[k * 512 + j];
    acc = fmaxf(acc, 0.0f);
    out[idx] = acc;
    atomicAdd(&st[j], acc);
    atomicAdd(&st[512 + j], acc * acc);
}

// ---------------- fc2: relu(bn(fch1) @ W + b), fused st5 ----------------
__global__ __launch_bounds__(256) void fc2_kernel(const float* __restrict__ in,
                           const float* __restrict__ st4, const float* __restrict__ g,
                           const float* __restrict__ bb, const float* __restrict__ W,
                           const float* __restrict__ bias, float* __restrict__ out,
                           float* __restrict__ st5) {
    __shared__ float scale[512], shift[512];
    int tid = threadIdx.x;
    for (int k = tid; k < 512; k += 256) {
        float mean = st4[k] * (1.0f / 32.0f);
        float var = st4[512 + k] * (1.0f / 32.0f) - mean * mean;
        float sc_ = rsqrtf(var + EPSV) * g[k];
        scale[k] = sc_;
        shift[k] = bb[k] - mean * sc_;
    }
    __syncthreads();
    int idx = blockIdx.x * 256 + tid;
    if (idx >= 32 * 256) return;
    int b = idx >> 8, j = idx & 255;
    float acc = bias[j];
    const float* ip = in + (b << 9);
    #pragma unroll 8
    for (int k = 0; k < 512; k++) acc += (ip[k] * scale[k] + shift[k]) * W[k * 256 + j];
    acc = fmaxf(acc, 0.0f);
    out[idx] = acc;
    atomicAdd(&st5[j], acc);
    atomicAdd(&st5[256 + j], acc * acc);
}

// ---------------- fc3: tanh(bn(fch2) @ W + b) ----------------
__global__ void fc3_kernel(const float* __restrict__ in, const float* __restrict__ st5,
                           const float* __restrict__ g, const float* __restrict__ bb,
                           const float* __restrict__ W, const float* __restrict__ bias,
                           float* __restrict__ out) {
    __shared__ float scale[256], shift[256];
    int tid = threadIdx.x;   // 128
    for (int k = tid; k < 256; k += 128) {
        float mean = st5[k] * (1.0f / 32.0f);
        float var = st5[256 + k] * (1.0f / 32.0f) - mean * mean;
        float sc_ = rsqrtf(var + EPSV) * g[k];
        scale[k] = sc_;
        shift[k] = bb[k] - mean * sc_;
    }
    __syncthreads();
    int b = tid >> 2, j = tid & 3;
    float acc = bias[j];
    const float* ip = in + (b << 8);
    #pragma unroll 8
    for (int k = 0; k < 256; k++) acc += (ip[k] * scale[k] + shift[k]) * W[k * 4 + j];
    out[tid] = tanhf(acc);
}

// =======================================================================
extern "C" void kernel_launch(void* const* d_in, const int* in_sizes, int n_in,
                              void* d_out, int out_size, void* d_ws, size_t ws_size,
                              hipStream_t stream) {
    const float* x       = (const float*)d_in[0];
    const float* basel   = (const float*)d_in[1];
    const float* cali    = (const float*)d_in[2];
    const float* Wq      = (const float*)d_in[3];
    const float* Wk      = (const float*)d_in[4];
    const float* Wq2     = (const float*)d_in[5];
    const float* Wk2     = (const float*)d_in[6];
    const float* Wv2     = (const float*)d_in[7];
    const float* Cv      = (const float*)d_in[8];
    const float* Wo1     = (const float*)d_in[9];
    const float* Wo2     = (const float*)d_in[10];
    const float* corr_w  = (const float*)d_in[11];
    const float* h_w     = (const float*)d_in[12];
    const float* corr    = (const float*)d_in[13];
    const float* g1      = (const float*)d_in[14];
    const float* b1      = (const float*)d_in[15];
    const float* ff1_w   = (const float*)d_in[16];
    const float* ff1_b   = (const float*)d_in[17];
    const float* g2      = (const float*)d_in[18];
    const float* b2      = (const float*)d_in[19];
    const float* ff2_w   = (const float*)d_in[20];
    const float* ff2_b   = (const float*)d_in[21];
    const float* g3      = (const float*)d_in[22];
    const float* b3      = (const float*)d_in[23];
    const float* tvw     = (const float*)d_in[24];
    const float* tvb     = (const float*)d_in[25];
    const float* beta1   = (const float*)d_in[26];
    const float* a1      = (const float*)d_in[27];
    const float* a2      = (const float*)d_in[28];
    const float* fc1_w   = (const float*)d_in[29];
    const float* fc1_b   = (const float*)d_in[30];
    const float* bnf1_g  = (const float*)d_in[31];
    const float* bnf1_b  = (const float*)d_in[32];
    const float* fc2_w   = (const float*)d_in[33];
    const float* fc2_b   = (const float*)d_in[34];
    const float* bnf2_g  = (const float*)d_in[35];
    const float* bnf2_b  = (const float*)d_in[36];
    const float* fc3_w   = (const float*)d_in[37];
    const float* fc3_b   = (const float*)d_in[38];
    float* out = (float*)d_out;
    float* ws = (float*)d_ws;

    // ---- workspace layout (float offsets) ----
    const size_t SCAL  = 0;         // 2
    const size_t PART  = 16;        // 128
    const size_t ST1   = 512;       // 162
    const size_t ST2   = 768;       // 512
    const size_t ST3   = 1536;      // 162
    const size_t ST4   = 1792;      // 1024
    const size_t ST5   = 2880;      // 512
    const size_t FEA   = 4096;      // 16384
    const size_t FCH1  = 20480;     // 16384
    const size_t FCH2  = 36864;     // 8192
    const size_t PEO   = 45056;     // 41472
    const size_t TX    = 90112;     // 1990656
    const size_t Q2O   = 2080768;   // 1327104   (reused: h1tmp)
    const size_t KCO   = 3407872;   // 1990656   (reused: Qs)
    const size_t VCO   = 5398528;   // 1990656   (reused: Ks)
    const size_t TMP2  = 7389184;   // 1327104   (reused: matin)
    const size_t H2O   = 8716288;   // 1327104   (reused: t3)
    const size_t XHO   = 10043392;  // 1327104
    const size_t BIASO = 11370496;  // 262144
    const size_t F1O   = 11632640;  // 4194304

    float* scal  = ws + SCAL;
    float* part  = ws + PART;
    float* st1   = ws + ST1;
    float* st2   = ws + ST2;
    float* st3   = ws + ST3;
    float* st4   = ws + ST4;
    float* st5   = ws + ST5;
    float* fea   = ws + FEA;
    float* fch1  = ws + FCH1;
    float* fch2  = ws + FCH2;
    float* pe    = ws + PEO;
    float* txall = ws + TX;
    float* Q2    = ws + Q2O;
    float* Kc    = ws + KCO;
    float* Vc    = ws + VCO;
    float* tmp2  = ws + TMP2;
    float* h2    = ws + H2O;
    float* xh    = ws + XHO;
    float* biasT = ws + BIASO;
    float* f1    = ws + F1O;
    float* h1tmp = Q2;     // reuse
    float* Qs    = Kc;     // reuse
    float* Ks    = Vc;     // reuse
    float* matin = tmp2;   // reuse
    float* t3    = h2;     // reuse

    // zero scal/part/stats region — capture-safe
    hipMemsetAsync(ws, 0, 4096 * sizeof(float), stream);

    minmax_part<<<64, 256, 0, stream>>>(x, part);
    minmax_fin<<<1, 64, 0, stream>>>(part, scal);

    pe_kernel<<<(512 * 81 + 255) / 256, 256, 0, stream>>>(pe);

    tokenize_kernel<<<(48 * 512 * 81 + 255) / 256, 256, 0, stream>>>(x, cali, scal, pe, txall);

    qkv2_kernel<<<384, 256, 0, stream>>>(txall, Wq2, Wk2, Wv2, Q2, Kc, Vc);

    attn2_kernel<<<(512 * 9 * 32) / 256, 256, 0, stream>>>(Q2, Kc, Vc, tmp2);

    h2xh_kernel<<<256, 256, 0, stream>>>(tmp2, Wo2, txall, h2, xh);

    qks_kernel<<<256, 256, 0, stream>>>(xh, Wq, Wk, Qs, Ks);

    biasmm_kernel<<<dim3(16, 16), dim3(16, 16), 0, stream>>>(corr, Cv, biasT);

    attn1_kernel<<<576, 256, 0, stream>>>(Qs, Ks, biasT, corr_w, h1tmp);

    h1o_kernel<<<256, 256, 0, stream>>>(h1tmp, Wo1, h2, txall, h_w, matin, st1);

    ff1_kernel<<<dim3(256, 2), 256, 0, stream>>>(matin, st1, g1, b1, ff1_w, ff1_b, f1, st2);

    ff2_kernel<<<512, 256, 0, stream>>>(f1, st2, g2, b2, ff2_w, ff2_b,
                                        matin, st1, g1, b1, t3, st3);

    token_kernel<<<512, 256, 0, stream>>>(t3, st3, g3, b3, tvw, tvb, beta1, basel, a1, a2, fea);

    fc1_kernel<<<64, 256, 0, stream>>>(fea, fc1_w, fc1_b, fch1, st4);

    fc2_kernel<<<32, 256, 0, stream>>>(fch1, st4, bnf1_g, bnf1_b, fc2_w, fc2_b, fch2, st5);

    fc3_kernel<<<1, 128, 0, stream>>>(fch2, st5, bnf2_g, bnf2_b, fc3_w, fc3_b, out);
}

// Round 4
// 519.964 us; speedup vs baseline: 2.4831x; 1.0300x over previous
//
#include <hip/hip_runtime.h>
#include <hip/hip_bf16.h>
#include <math.h>

#define EPSV 1e-5f

// ---------------- sizes ----------------
// B=32 Bc=16 L=2048 TOKEN=40 STRIDE=4 D=81 H=9 dk=9 S=512 FF=256 FC1=512 FC2=256 Y=4

// ---------------- minmax: two-stage ----------------
__global__ void minmax_part(const float* __restrict__ x, float* __restrict__ part) {
    __shared__ float smin[256], smax[256];
    int tid = threadIdx.x;
    float mn = 1e30f, mx = -1e30f;
    for (int i = blockIdx.x * 256 + tid; i < 32 * 2008; i += 64 * 256) {
        int b = i / 2008, c = i % 2008 + 20;
        float v = x[b * 2048 + c];
        mn = fminf(mn, v); mx = fmaxf(mx, v);
    }
    smin[tid] = mn; smax[tid] = mx; __syncthreads();
    for (int off = 128; off > 0; off >>= 1) {
        if (tid < off) { smin[tid] = fminf(smin[tid], smin[tid + off]); smax[tid] = fmaxf(smax[tid], smax[tid + off]); }
        __syncthreads();
    }
    if (tid == 0) { part[blockIdx.x] = smin[0]; part[64 + blockIdx.x] = smax[0]; }
}

__global__ void minmax_fin(const float* __restrict__ part, float* __restrict__ scal) {
    __shared__ float smn[64], smx[64];
    int tid = threadIdx.x;
    smn[tid] = part[tid]; smx[tid] = part[64 + tid]; __syncthreads();
    for (int off = 32; off > 0; off >>= 1) {
        if (tid < off) { smn[tid] = fminf(smn[tid], smn[tid + off]); smx[tid] = fmaxf(smx[tid], smx[tid + off]); }
        __syncthreads();
    }
    if (tid == 0) { scal[0] = smn[0]; scal[1] = smx[0] - smn[0]; }
}

// ---------------- PE table (512 x 81) ----------------
__global__ void pe_kernel(float* __restrict__ pe) {
    int idx = blockIdx.x * blockDim.x + threadIdx.x;
    if (idx >= 512 * 81) return;
    int d = idx % 81, s = idx / 81;
    int j = d >> 1;
    float dv = __expf(-9.210340371976184f * (2.0f * (float)j) / 81.0f);
    float ang = (float)s * dv;
    pe[idx] = (d & 1) ? cosf(ang) : sinf(ang);
}

// ---------------- tokenize + add PE ----------------
__global__ void tokenize_kernel(const float* __restrict__ x, const float* __restrict__ cali,
                                const float* __restrict__ scal, const float* __restrict__ pe,
                                float* __restrict__ txall) {
    int idx = blockIdx.x * blockDim.x + threadIdx.x;
    if (idx >= 48 * 512 * 81) return;
    int d = idx % 81;
    int s = (idx / 81) % 512;
    int r = idx / (81 * 512);
    float xm = scal[0], inv_xs = 1.0f / scal[1];
    int oc = s * 4 + d - 40;
    float val = 0.0f;
    if (oc >= 0 && oc < 2048) {
        float sv = (r < 32) ? x[r * 2048 + oc] : cali[(r - 32) * 2048 + oc];
        val = (sv - xm) * inv_xs;
    }
    txall[idx] = val + pe[s * 81 + d];
}

// ---------------- qkv2: 64 rows/block, W in LDS, 4-row reg tile ----------------
__global__ __launch_bounds__(256) void qkv2_kernel(const float* __restrict__ txall,
                            const float* __restrict__ Wq2, const float* __restrict__ Wk2,
                            const float* __restrict__ Wv2,
                            float* __restrict__ Q2, float* __restrict__ Kc, float* __restrict__ Vc) {
    __shared__ float rows_[64 * 81];
    __shared__ float Wl[6561];
    int blk = blockIdx.x;            // 0..383
    int row0 = blk * 64;             // k*512+s flattened
    int k = row0 >> 9;               // block-uniform
    int s0 = row0 & 511;
    int tid = threadIdx.x;
    for (int i = tid; i < 64 * 81; i += 256) rows_[i] = txall[row0 * 81 + i];
    for (int t = 0; t < 3; t++) {
        if (t == 0 && k >= 32) continue;   // block-uniform
        const float* W = (t == 0) ? Wq2 : (t == 1) ? Wk2 : Wv2;
        __syncthreads();
        for (int i = tid; i < 6561; i += 256) {
            int e = i / 81, hd = i % 81, h = hd / 9, d = hd % 9;
            Wl[i] = W[h * 729 + e * 9 + d];     // Wl[e*81+hd]
        }
        __syncthreads();
        for (int o = tid; o < 16 * 81; o += 256) {
            int r4 = o / 81, hd = o % 81;
            float a0 = 0, a1 = 0, a2 = 0, a3 = 0;
            const float* rp = rows_ + r4 * 4 * 81;
            #pragma unroll 3
            for (int e = 0; e < 81; e++) {
                float w = Wl[e * 81 + hd];
                a0 += rp[e] * w; a1 += rp[81 + e] * w;
                a2 += rp[162 + e] * w; a3 += rp[243 + e] * w;
            }
            int h = hd / 9, d = hd % 9;
            int sb = s0 + r4 * 4;
            float av[4] = {a0, a1, a2, a3};
            #pragma unroll
            for (int j = 0; j < 4; j++) {
                int s = sb + j;
                if (t == 0)      Q2[((s * 9 + h) * 32 + k) * 9 + d] = av[j];
                else if (t == 1) Kc[((s * 9 + h) * 48 + k) * 9 + d] = av[j];
                else             Vc[((s * 9 + h) * 48 + k) * 9 + d] = av[j];
            }
        }
    }
}

// ---------------- attention-2 (masked: key==b or key>=32) ----------------
__global__ void attn2_kernel(const float* __restrict__ Q2, const float* __restrict__ Kc,
                             const float* __restrict__ Vc, float* __restrict__ tmp2) {
    int tid = blockIdx.x * blockDim.x + threadIdx.x;
    if (tid >= 512 * 9 * 32) return;
    int b = tid & 31;
    int h = (tid >> 5) % 9;
    int s = tid / 288;
    const float* q = Q2 + ((s * 9 + h) * 32 + b) * 9;
    float qr[9];
    #pragma unroll
    for (int d = 0; d < 9; d++) qr[d] = q[d];
    const float* Kb = Kc + (s * 9 + h) * 48 * 9;
    const float* Vb = Vc + (s * 9 + h) * 48 * 9;
    float sc[17];
    float m = -1e30f;
    const float inv3 = 1.0f / 3.0f;
    #pragma unroll
    for (int j = 0; j < 17; j++) {
        int k = (j == 0) ? b : 31 + j;
        const float* kp = Kb + k * 9;
        float acc = 0.0f;
        #pragma unroll
        for (int d = 0; d < 9; d++) acc += qr[d] * kp[d];
        acc *= inv3;
        sc[j] = acc; m = fmaxf(m, acc);
    }
    float l = 0.0f, outv[9];
    #pragma unroll
    for (int d = 0; d < 9; d++) outv[d] = 0.0f;
    #pragma unroll
    for (int j = 0; j < 17; j++) {
        float p = __expf(sc[j] - m); l += p;
        int k = (j == 0) ? b : 31 + j;
        const float* vp = Vb + k * 9;
        #pragma unroll
        for (int d = 0; d < 9; d++) outv[d] += p * vp[d];
    }
    float invl = 1.0f / l;
    float* op = tmp2 + (b * 512 + s) * 81 + h * 9;
    #pragma unroll
    for (int d = 0; d < 9; d++) op[d] = outv[d] * invl;
}

// ---------------- h2 = tmp2 @ Wo2 ; xh = tx + h2  (64 rows/block) ----------------
__global__ __launch_bounds__(256) void h2xh_kernel(const float* __restrict__ tmp2,
                            const float* __restrict__ Wo2, const float* __restrict__ txall,
                            float* __restrict__ h2, float* __restrict__ xh) {
    __shared__ float rows_[64 * 81];
    __shared__ float Wl[6561];
    int row0 = blockIdx.x * 64;
    int tid = threadIdx.x;
    for (int i = tid; i < 64 * 81; i += 256) rows_[i] = tmp2[row0 * 81 + i];
    for (int i = tid; i < 6561; i += 256) Wl[i] = Wo2[i];
    __syncthreads();
    for (int o = tid; o < 16 * 81; o += 256) {
        int r4 = o / 81, c = o % 81;
        float a0 = 0, a1 = 0, a2 = 0, a3 = 0;
        const float* rp = rows_ + r4 * 4 * 81;
        #pragma unroll 3
        for (int e = 0; e < 81; e++) {
            float w = Wl[e * 81 + c];
            a0 += rp[e] * w; a1 += rp[81 + e] * w;
            a2 += rp[162 + e] * w; a3 += rp[243 + e] * w;
        }
        float av[4] = {a0, a1, a2, a3};
        #pragma unroll
        for (int j = 0; j < 4; j++) {
            int idx = (row0 + r4 * 4 + j) * 81 + c;
            h2[idx] = av[j];
            xh[idx] = txall[idx] + av[j];
        }
    }
}

// ---------------- Qs/Ks projections (Vs == Qs) ----------------
__global__ __launch_bounds__(256) void qks_kernel(const float* __restrict__ xh,
                           const float* __restrict__ Wq, const float* __restrict__ Wk,
                           float* __restrict__ Qs, float* __restrict__ Ks) {
    __shared__ float rows_[64 * 81];
    __shared__ float Wl[6561];
    int blk = blockIdx.x;            // 0..255
    int row0 = blk * 64;             // b*512+s
    int b = row0 >> 9;
    int s0 = row0 & 511;
    int tid = threadIdx.x;
    for (int i = tid; i < 64 * 81; i += 256) rows_[i] = xh[row0 * 81 + i];
    for (int t = 0; t < 2; t++) {
        const float* W = (t == 0) ? Wq : Wk;
        __syncthreads();
        for (int i = tid; i < 6561; i += 256) {
            int e = i / 81, hd = i % 81, h = hd / 9, d = hd % 9;
            Wl[i] = W[h * 729 + e * 9 + d];
        }
        __syncthreads();
        float* dst = (t == 0) ? Qs : Ks;
        for (int o = tid; o < 16 * 81; o += 256) {
            int r4 = o / 81, hd = o % 81;
            float a0 = 0, a1 = 0, a2 = 0, a3 = 0;
            const float* rp = rows_ + r4 * 4 * 81;
            #pragma unroll 3
            for (int e = 0; e < 81; e++) {
                float w = Wl[e * 81 + hd];
                a0 += rp[e] * w; a1 += rp[81 + e] * w;
                a2 += rp[162 + e] * w; a3 += rp[243 + e] * w;
            }
            int h = hd / 9, d = hd % 9;
            int sb = s0 + r4 * 4;
            float av[4] = {a0, a1, a2, a3};
            #pragma unroll
            for (int j = 0; j < 4; j++)
                dst[((b * 9 + h) * 512 + (sb + j)) * 9 + d] = av[j];
        }
    }
}

// ---------------- biasT = (corr @ Cv)^T / sqrt(S) ----------------
__global__ __launch_bounds__(256) void biasmm_kernel(const float* __restrict__ corr,
                              const float* __restrict__ Cv, float* __restrict__ biasT) {
    __shared__ float As[32][33];
    __shared__ float Bs[32][33];
    int tx = threadIdx.x, ty = threadIdx.y;   // 16 x 16
    int tid = ty * 16 + tx;
    int t0 = blockIdx.y * 32, s0 = blockIdx.x * 32;
    float a00 = 0, a01 = 0, a10 = 0, a11 = 0;
    for (int k0 = 0; k0 < 512; k0 += 32) {
        for (int ii = tid; ii < 1024; ii += 256) {
            int r = ii >> 5, c = ii & 31;
            As[r][c] = Cv[(k0 + r) * 512 + t0 + c];
            Bs[r][c] = corr[(s0 + r) * 512 + k0 + c];
        }
        __syncthreads();
        #pragma unroll
        for (int kk = 0; kk < 32; kk++) {
            float b0 = Bs[tx][kk], b1 = Bs[tx + 16][kk];
            float c0 = As[kk][ty], c1 = As[kk][ty + 16];
            a00 += c0 * b0; a01 += c0 * b1; a10 += c1 * b0; a11 += c1 * b1;
        }
        __syncthreads();
    }
    const float invs = 0.04419417382415922f;   // 1/sqrt(512)
    biasT[(t0 + ty) * 512 + s0 + tx]            = a00 * invs;
    biasT[(t0 + ty) * 512 + s0 + tx + 16]       = a01 * invs;
    biasT[(t0 + ty + 16) * 512 + s0 + tx]       = a10 * invs;
    biasT[(t0 + ty + 16) * 512 + s0 + tx + 16]  = a11 * invs;
}

// ---------------- attention-1: 4 queries/thread, 4-way key split, in-block merge ----------------
// block = (bh, qhalf): 256 threads = 64 q-threads x 4 key-quarters
// thread (qt, kq): queries q = qhalf*256 + qt + j*64 (j=0..3), keys [kq*128, kq*128+128)
__global__ __launch_bounds__(256) void attn1_kernel(const float* __restrict__ Qs,
                                                    const float* __restrict__ Ks,
                                                    const float* __restrict__ biasT,
                                                    const float* __restrict__ cwp,
                                                    float* __restrict__ h1tmp) {
    int blk = blockIdx.x;          // 0..575
    int bh = blk >> 1;             // b*9+h
    int qhalf = blk & 1;
    int b = bh / 9, h = bh % 9;
    __shared__ float sh[12288];    // 48KB: K [512][12] then V [512][12]; reused for merge
    float (*Ksh)[12] = (float(*)[12])sh;
    float (*Vsh)[12] = (float(*)[12])(sh + 6144);
    int tid = threadIdx.x;
    int qt = tid & 63, kq = tid >> 6;
    const float* Kb = Ks + bh * 4608;
    const float* Qb = Qs + bh * 4608;
    for (int i = tid; i < 4608; i += 256) {
        int r = i / 9, c = i % 9;
        Ksh[r][c] = Kb[i];
        Vsh[r][c] = Qb[i];   // Vs == Qs
    }
    __syncthreads();
    // load 4 query vectors from global (L2)
    int q0 = qhalf * 256 + qt;
    float qv[4][9];
    #pragma unroll
    for (int j = 0; j < 4; j++) {
        const float* qp = Qb + (q0 + j * 64) * 9;
        #pragma unroll
        for (int d = 0; d < 9; d++) qv[j][d] = qp[d];
    }
    float cw = cwp[0];
    float c1 = (1.0f - cw) / 3.0f;
    float m[4], l[4], acc[4][9];
    #pragma unroll
    for (int j = 0; j < 4; j++) {
        m[j] = -1e30f; l[j] = 0.0f;
        #pragma unroll
        for (int d = 0; d < 9; d++) acc[j][d] = 0.0f;
    }
    int t0beg = kq * 128;
    for (int t0 = t0beg; t0 < t0beg + 128; t0 += 8) {
        float sc[8][4];
        #pragma unroll
        for (int tt = 0; tt < 8; tt++) {
            const float4* kp = reinterpret_cast<const float4*>(Ksh[t0 + tt]);
            float4 k0 = kp[0], k1 = kp[1], k2 = kp[2];
            const float* brow = biasT + ((t0 + tt) << 9) + q0;
            #pragma unroll
            for (int j = 0; j < 4; j++) {
                float s = qv[j][0] * k0.x + qv[j][1] * k0.y + qv[j][2] * k0.z + qv[j][3] * k0.w
                        + qv[j][4] * k1.x + qv[j][5] * k1.y + qv[j][6] * k1.z + qv[j][7] * k1.w
                        + qv[j][8] * k2.x;
                sc[tt][j] = c1 * s + cw * brow[j * 64];
            }
        }
        // per-query chunk max + rescale
        #pragma unroll
        for (int j = 0; j < 4; j++) {
            float cm = sc[0][j];
            #pragma unroll
            for (int tt = 1; tt < 8; tt++) cm = fmaxf(cm, sc[tt][j]);
            float nm = fmaxf(m[j], cm);
            float f = __expf(m[j] - nm);
            m[j] = nm;
            l[j] *= f;
            #pragma unroll
            for (int d = 0; d < 9; d++) acc[j][d] *= f;
        }
        #pragma unroll
        for (int tt = 0; tt < 8; tt++) {
            const float4* vp = reinterpret_cast<const float4*>(Vsh[t0 + tt]);
            float4 v0 = vp[0], v1 = vp[1], v2 = vp[2];
            #pragma unroll
            for (int j = 0; j < 4; j++) {
                float p = __expf(sc[tt][j] - m[j]);
                l[j] += p;
                acc[j][0] += p * v0.x; acc[j][1] += p * v0.y; acc[j][2] += p * v0.z;
                acc[j][3] += p * v0.w; acc[j][4] += p * v1.x; acc[j][5] += p * v1.y;
                acc[j][6] += p * v1.z; acc[j][7] += p * v1.w; acc[j][8] += p * v2.x;
            }
        }
    }
    // in-block merge of the 4 key-quarter partials (reuse sh: 256*4*11 = 11264 <= 12288)
    __syncthreads();
    #pragma unroll
    for (int j = 0; j < 4; j++) {
        int ql = qt + j * 64;
        float* P = sh + (ql * 4 + kq) * 11;
        P[0] = m[j]; P[1] = l[j];
        #pragma unroll
        for (int d = 0; d < 9; d++) P[2 + d] = acc[j][d];
    }
    __syncthreads();
    {
        int ql = tid;
        const float* P = sh + ql * 44;
        float M = fmaxf(fmaxf(P[0], P[11]), fmaxf(P[22], P[33]));
        float L = 0.0f;
        float o[9];
        #pragma unroll
        for (int d = 0; d < 9; d++) o[d] = 0.0f;
        #pragma unroll
        for (int k = 0; k < 4; k++) {
            const float* Pk = P + k * 11;
            float w = __expf(Pk[0] - M);
            L += w * Pk[1];
            #pragma unroll
            for (int d = 0; d < 9; d++) o[d] += w * Pk[2 + d];
        }
        float invl = 1.0f / L;
        int q = qhalf * 256 + ql;
        float* op = h1tmp + (b * 512 + q) * 81 + h * 9;
        #pragma unroll
        for (int d = 0; d < 9; d++) op[d] = o[d] * invl;
    }
}

// ---------------- matin = (1-hw)*(h1tmp@Wo1) + hw*h2 + tx ; fused st1 partials ----------------
__global__ __launch_bounds__(256) void h1o_kernel(const float* __restrict__ h1tmp,
                           const float* __restrict__ Wo1, const float* __restrict__ h2,
                           const float* __restrict__ txall, const float* __restrict__ hwp,
                           float* __restrict__ matin, float* __restrict__ st1) {
    __shared__ float rows_[64 * 81];
    __shared__ float Wl[6561];
    __shared__ float ssum[81], ssq[81];
    int row0 = blockIdx.x * 64;
    int tid = threadIdx.x;
    if (tid < 81) { ssum[tid] = 0.0f; ssq[tid] = 0.0f; }
    for (int i = tid; i < 64 * 81; i += 256) rows_[i] = h1tmp[row0 * 81 + i];
    for (int i = tid; i < 6561; i += 256) Wl[i] = Wo1[i];
    __syncthreads();
    float hw = hwp[0];
    float onemhw = 1.0f - hw;
    for (int o = tid; o < 16 * 81; o += 256) {
        int r4 = o / 81, c = o % 81;
        float a0 = 0, a1 = 0, a2 = 0, a3 = 0;
        const float* rp = rows_ + r4 * 4 * 81;
        #pragma unroll 3
        for (int e = 0; e < 81; e++) {
            float w = Wl[e * 81 + c];
            a0 += rp[e] * w; a1 += rp[81 + e] * w;
            a2 += rp[162 + e] * w; a3 += rp[243 + e] * w;
        }
        float av[4] = {a0, a1, a2, a3};
        float ls = 0.0f, lq = 0.0f;
        #pragma unroll
        for (int j = 0; j < 4; j++) {
            int idx = (row0 + r4 * 4 + j) * 81 + c;
            float v = onemhw * av[j] + hw * h2[idx] + txall[idx];
            matin[idx] = v;
            ls += v; lq += v * v;
        }
        atomicAdd(&ssum[c], ls);
        atomicAdd(&ssq[c], lq);
    }
    __syncthreads();
    if (tid < 81) {
        atomicAdd(&st1[tid], ssum[tid]);
        atomicAdd(&st1[81 + tid], ssq[tid]);
    }
}

// ---------------- ff1: f1 = relu(bn1(matin) @ ff1_w + b) ; fused st2 partials ----------------
__global__ __launch_bounds__(256) void ff1_kernel(const float* __restrict__ matin,
                           const float* __restrict__ st1, const float* __restrict__ g1,
                           const float* __restrict__ b1, const float* __restrict__ W,
                           const float* __restrict__ bias, float* __restrict__ f1,
                           float* __restrict__ st2) {
    __shared__ float rows_[64 * 81];
    __shared__ float Wl[81 * 128];
    __shared__ float s2s[128], s2q[128];
    int row0 = blockIdx.x * 64;
    int c0 = blockIdx.y * 128;
    int tid = threadIdx.x;
    const float invN = 1.0f / 16384.0f;
    if (tid < 128) { s2s[tid] = 0.0f; s2q[tid] = 0.0f; }
    for (int i = tid; i < 64 * 81; i += 256) {
        int c = i % 81;
        float mean = st1[c] * invN;
        float var = st1[81 + c] * invN - mean * mean;
        rows_[i] = (matin[row0 * 81 + i] - mean) * rsqrtf(var + EPSV) * g1[c] + b1[c];
    }
    for (int i = tid; i < 81 * 128; i += 256) {
        int e = i >> 7, cc = i & 127;
        Wl[i] = W[e * 256 + c0 + cc];
    }
    __syncthreads();
    for (int o = tid; o < 16 * 128; o += 256) {
        int r4 = o >> 7, cc = o & 127;
        float bv = bias[c0 + cc];
        float a0 = bv, a1 = bv, a2 = bv, a3 = bv;
        const float* rp = rows_ + r4 * 4 * 81;
        #pragma unroll 3
        for (int e = 0; e < 81; e++) {
            float w = Wl[(e << 7) + cc];
            a0 += rp[e] * w; a1 += rp[81 + e] * w;
            a2 += rp[162 + e] * w; a3 += rp[243 + e] * w;
        }
        a0 = fmaxf(a0, 0.0f); a1 = fmaxf(a1, 0.0f);
        a2 = fmaxf(a2, 0.0f); a3 = fmaxf(a3, 0.0f);
        int base = (row0 + r4 * 4) * 256 + c0 + cc;
        f1[base]       = a0;
        f1[base + 256] = a1;
        f1[base + 512] = a2;
        f1[base + 768] = a3;
        atomicAdd(&s2s[cc], a0 + a1 + a2 + a3);
        atomicAdd(&s2q[cc], a0 * a0 + a1 * a1 + a2 * a2 + a3 * a3);
    }
    __syncthreads();
    if (tid < 128) {
        atomicAdd(&st2[c0 + tid], s2s[tid]);
        atomicAdd(&st2[256 + c0 + tid], s2q[tid]);
    }
}

// ---------------- ff2: t3 = bn1(matin) + relu(bn2(f1) @ ff2_w + b) ; fused st3 ----------------
__global__ __launch_bounds__(256) void ff2_kernel(const float* __restrict__ f1,
                           const float* __restrict__ st2, const float* __restrict__ g2,
                           const float* __restrict__ b2, const float* __restrict__ W,
                           const float* __restrict__ bias, const float* __restrict__ matin,
                           const float* __restrict__ st1, const float* __restrict__ g1,
                           const float* __restrict__ b1, float* __restrict__ t3,
                           float* __restrict__ st3) {
    __shared__ float rows_[32 * 128];
    __shared__ float Wl[128 * 81];
    __shared__ float s3s[81], s3q[81];
    int row0 = blockIdx.x * 32;
    int tid = threadIdx.x;
    const float invN = 1.0f / 16384.0f;
    if (tid < 81) { s3s[tid] = 0.0f; s3q[tid] = 0.0f; }
    float acc[3][4];
    #pragma unroll
    for (int oi = 0; oi < 3; oi++) {
        int o = tid + oi * 256;
        float bv = (o < 648) ? bias[o % 81] : 0.0f;
        #pragma unroll
        for (int j = 0; j < 4; j++) acc[oi][j] = bv;
    }
    for (int half = 0; half < 2; half++) {
        __syncthreads();
        for (int i = tid; i < 32 * 128; i += 256) {
            int c = half * 128 + (i & 127);
            float mean = st2[c] * invN;
            float var = st2[256 + c] * invN - mean * mean;
            rows_[i] = (f1[(row0 + (i >> 7)) * 256 + c] - mean) * rsqrtf(var + EPSV) * g2[c] + b2[c];
        }
        for (int i = tid; i < 128 * 81; i += 256) Wl[i] = W[half * 128 * 81 + i];
        __syncthreads();
        #pragma unroll
        for (int oi = 0; oi < 3; oi++) {
            int o = tid + oi * 256;
            if (o < 648) {
                int r4 = o / 81, c = o % 81;
                const float* rp = rows_ + r4 * 4 * 128;
                #pragma unroll 4
                for (int e = 0; e < 128; e++) {
                    float w = Wl[e * 81 + c];
                    acc[oi][0] += rp[e] * w;       acc[oi][1] += rp[128 + e] * w;
                    acc[oi][2] += rp[256 + e] * w; acc[oi][3] += rp[384 + e] * w;
                }
            }
        }
    }
    #pragma unroll
    for (int oi = 0; oi < 3; oi++) {
        int o = tid + oi * 256;
        if (o < 648) {
            int r4 = o / 81, c = o % 81;
            float mean = st1[c] * invN;
            float var = st1[81 + c] * invN - mean * mean;
            float rstd = rsqrtf(var + EPSV);
            float ls = 0.0f, lq = 0.0f;
            #pragma unroll
            for (int j = 0; j < 4; j++) {
                int idx = (row0 + r4 * 4 + j) * 81 + c;
                float ma = (matin[idx] - mean) * rstd * g1[c] + b1[c];
                float v = ma + fmaxf(acc[oi][j], 0.0f);
                t3[idx] = v;
                ls += v; lq += v * v;
            }
            atomicAdd(&s3s[c], ls);
            atomicAdd(&s3q[c], lq);
        }
    }
    __syncthreads();
    if (tid < 81) {
        atomicAdd(&st3[tid], s3s[tid]);
        atomicAdd(&st3[81 + tid], s3q[tid]);
    }
}

// ---------------- token pooling: 32 rows/block, 8 lanes/row ----------------
__global__ __launch_bounds__(256) void token_kernel(const float* __restrict__ t3,
                             const float* __restrict__ st3, const float* __restrict__ g3,
                             const float* __restrict__ b3, const float* __restrict__ tvw,
                             const float* __restrict__ tvb, const float* __restrict__ beta1,
                             const float* __restrict__ basel, const float* __restrict__ a1p,
                             const float* __restrict__ a2p, float* __restrict__ fea) {
    __shared__ float rows_[32 * 81];
    __shared__ float Wu[6561];
    __shared__ float Wv[6561];
    int row0 = blockIdx.x * 32;
    int tid = threadIdx.x;
    const float invN = 1.0f / 16384.0f;
    for (int i = tid; i < 32 * 81; i += 256) {
        int c = i % 81;
        float mean = st3[c] * invN;
        float var = st3[81 + c] * invN - mean * mean;
        rows_[i] = (t3[row0 * 81 + i] - mean) * rsqrtf(var + EPSV) * g3[c] + b3[c];
    }
    for (int i = tid; i < 6561; i += 256) { Wu[i] = tvw[i]; Wv[i] = beta1[i]; }
    __syncthreads();
    int r = tid >> 3, j = tid & 7;
    const float* rp = rows_ + r * 81;
    float u[11], v[11];
    #pragma unroll
    for (int dd = 0; dd < 11; dd++) {
        int d = j + dd * 8;
        u[dd] = (d < 81) ? tvb[d] : 0.0f;
        v[dd] = (d < 81) ? 0.0f : -1e30f;
    }
    for (int e = 0; e < 81; e++) {
        float rv = rp[e];
        #pragma unroll
        for (int dd = 0; dd < 11; dd++) {
            int d = j + dd * 8;
            if (d < 81) {
                u[dd] += rv * Wu[e * 81 + d];
                v[dd] += rv * Wv[e * 81 + d];
            }
        }
    }
    float mx = -1e30f;
    #pragma unroll
    for (int dd = 0; dd < 11; dd++) mx = fmaxf(mx, v[dd]);
    #pragma unroll
    for (int msk = 1; msk < 8; msk <<= 1) mx = fmaxf(mx, __shfl_xor(mx, msk, 8));
    float sp = 0.0f, sup = 0.0f;
    #pragma unroll
    for (int dd = 0; dd < 11; dd++) {
        float p = __expf(v[dd] - mx);
        sp += p; sup += u[dd] * p;
    }
    #pragma unroll
    for (int msk = 1; msk < 8; msk <<= 1) {
        sp  += __shfl_xor(sp, msk, 8);
        sup += __shfl_xor(sup, msk, 8);
    }
    if (j == 0) {
        int rg = row0 + r;
        int b = rg >> 9, s = rg & 511;
        fea[rg] = a1p[0] * (sup / sp) + a2p[0] * basel[b * 2048 + s * 4];
    }
}

// ---------------- fc1: relu(fea @ W + b), fused st4 ----------------
__global__ void fc1_kernel(const float* __restrict__ in, const float* __restrict__ W,
                           const float* __restrict__ bias, float* __restrict__ out,
                           float* __restrict__ st) {
    int idx = blockIdx.x * blockDim.x + threadIdx.x;
    if (idx >= 32 * 512) return;
    int b = idx >> 9, j = idx & 511;
    float acc = bias[j];
    const float* ip = in + (b << 9);
    #pragma unroll 8
    for (int k = 0; k < 512; k++) acc += ip[k] * W[k * 512 + j];
    acc = fmaxf(acc, 0.0f);
    out[idx] = acc;
    atomicAdd(&st[j], acc);
    atomicAdd(&st[512 + j], acc * acc);
}

// ---------------- fc2: relu(bn(fch1) @ W + b), fused st5 ----------------
__global__ __launch_bounds__(256) void fc2_kernel(const float* __restrict__ in,
                           const float* __restrict__ st4, const float* __restrict__ g,
                           const float* __restrict__ bb, const float* __restrict__ W,
                           const float* __restrict__ bias, float* __restrict__ out,
                           float* __restrict__ st5) {
    __shared__ float scale[512], shift[512];
    int tid = threadIdx.x;
    for (int k = tid; k < 512; k += 256) {
        float mean = st4[k] * (1.0f / 32.0f);
        float var = st4[512 + k] * (1.0f / 32.0f) - mean * mean;
        float sc_ = rsqrtf(var + EPSV) * g[k];
        scale[k] = sc_;
        shift[k] = bb[k] - mean * sc_;
    }
    __syncthreads();
    int idx = blockIdx.x * 256 + tid;
    if (idx >= 32 * 256) return;
    int b = idx >> 8, j = idx & 255;
    float acc = bias[j];
    const float* ip = in + (b << 9);
    #pragma unroll 8
    for (int k = 0; k < 512; k++) acc += (ip[k] * scale[k] + shift[k]) * W[k * 256 + j];
    acc = fmaxf(acc, 0.0f);
    out[idx] = acc;
    atomicAdd(&st5[j], acc);
    atomicAdd(&st5[256 + j], acc * acc);
}

// ---------------- fc3: tanh(bn(fch2) @ W + b) ----------------
__global__ void fc3_kernel(const float* __restrict__ in, const float* __restrict__ st5,
                           const float* __restrict__ g, const float* __restrict__ bb,
                           const float* __restrict__ W, const float* __restrict__ bias,
                           float* __restrict__ out) {
    __shared__ float scale[256], shift[256];
    int tid = threadIdx.x;   // 128
    for (int k = tid; k < 256; k += 128) {
        float mean = st5[k] * (1.0f / 32.0f);
        float var = st5[256 + k] * (1.0f / 32.0f) - mean * mean;
        float sc_ = rsqrtf(var + EPSV) * g[k];
        scale[k] = sc_;
        shift[k] = bb[k] - mean * sc_;
    }
    __syncthreads();
    int b = tid >> 2, j = tid & 3;
    float acc = bias[j];
    const float* ip = in + (b << 8);
    #pragma unroll 8
    for (int k = 0; k < 256; k++) acc += (ip[k] * scale[k] + shift[k]) * W[k * 4 + j];
    out[tid] = tanhf(acc);
}

// =======================================================================
extern "C" void kernel_launch(void* const* d_in, const int* in_sizes, int n_in,
                              void* d_out, int out_size, void* d_ws, size_t ws_size,
                              hipStream_t stream) {
    const float* x       = (const float*)d_in[0];
    const float* basel   = (const float*)d_in[1];
    const float* cali    = (const float*)d_in[2];
    const float* Wq      = (const float*)d_in[3];
    const float* Wk      = (const float*)d_in[4];
    const float* Wq2     = (const float*)d_in[5];
    const float* Wk2     = (const float*)d_in[6];
    const float* Wv2     = (const float*)d_in[7];
    const float* Cv      = (const float*)d_in[8];
    const float* Wo1     = (const float*)d_in[9];
    const float* Wo2     = (const float*)d_in[10];
    const float* corr_w  = (const float*)d_in[11];
    const float* h_w     = (const float*)d_in[12];
    const float* corr    = (const float*)d_in[13];
    const float* g1      = (const float*)d_in[14];
    const float* b1      = (const float*)d_in[15];
    const float* ff1_w   = (const float*)d_in[16];
    const float* ff1_b   = (const float*)d_in[17];
    const float* g2      = (const float*)d_in[18];
    const float* b2      = (const float*)d_in[19];
    const float* ff2_w   = (const float*)d_in[20];
    const float* ff2_b   = (const float*)d_in[21];
    const float* g3      = (const float*)d_in[22];
    const float* b3      = (const float*)d_in[23];
    const float* tvw     = (const float*)d_in[24];
    const float* tvb     = (const float*)d_in[25];
    const float* beta1   = (const float*)d_in[26];
    const float* a1      = (const float*)d_in[27];
    const float* a2      = (const float*)d_in[28];
    const float* fc1_w   = (const float*)d_in[29];
    const float* fc1_b   = (const float*)d_in[30];
    const float* bnf1_g  = (const float*)d_in[31];
    const float* bnf1_b  = (const float*)d_in[32];
    const float* fc2_w   = (const float*)d_in[33];
    const float* fc2_b   = (const float*)d_in[34];
    const float* bnf2_g  = (const float*)d_in[35];
    const float* bnf2_b  = (const float*)d_in[36];
    const float* fc3_w   = (const float*)d_in[37];
    const float* fc3_b   = (const float*)d_in[38];
    float* out = (float*)d_out;
    float* ws = (float*)d_ws;

    // ---- workspace layout (float offsets) ----
    const size_t SCAL  = 0;         // 2
    const size_t PART  = 16;        // 128
    const size_t ST1   = 512;       // 162
    const size_t ST2   = 768;       // 512
    const size_t ST3   = 1536;      // 162
    const size_t ST4   = 1792;      // 1024
    const size_t ST5   = 2880;      // 512
    const size_t FEA   = 4096;      // 16384
    const size_t FCH1  = 20480;     // 16384
    const size_t FCH2  = 36864;     // 8192
    const size_t PEO   = 45056;     // 41472
    const size_t TX    = 90112;     // 1990656
    const size_t Q2O   = 2080768;   // 1327104   (reused: h1tmp)
    const size_t KCO   = 3407872;   // 1990656   (reused: Qs)
    const size_t VCO   = 5398528;   // 1990656   (reused: Ks)
    const size_t TMP2  = 7389184;   // 1327104   (reused: matin)
    const size_t H2O   = 8716288;   // 1327104   (reused: t3)
    const size_t XHO   = 10043392;  // 1327104
    const size_t BIASO = 11370496;  // 262144
    const size_t F1O   = 11632640;  // 4194304

    float* scal  = ws + SCAL;
    float* part  = ws + PART;
    float* st1   = ws + ST1;
    float* st2   = ws + ST2;
    float* st3   = ws + ST3;
    float* st4   = ws + ST4;
    float* st5   = ws + ST5;
    float* fea   = ws + FEA;
    float* fch1  = ws + FCH1;
    float* fch2  = ws + FCH2;
    float* pe    = ws + PEO;
    float* txall = ws + TX;
    float* Q2    = ws + Q2O;
    float* Kc    = ws + KCO;
    float* Vc    = ws + VCO;
    float* tmp2  = ws + TMP2;
    float* h2    = ws + H2O;
    float* xh    = ws + XHO;
    float* biasT = ws + BIASO;
    float* f1    = ws + F1O;
    float* h1tmp = Q2;     // reuse
    float* Qs    = Kc;     // reuse
    float* Ks    = Vc;     // reuse
    float* matin = tmp2;   // reuse
    float* t3    = h2;     // reuse

    // zero scal/part/stats region — capture-safe
    hipMemsetAsync(ws, 0, 4096 * sizeof(float), stream);

    minmax_part<<<64, 256, 0, stream>>>(x, part);
    minmax_fin<<<1, 64, 0, stream>>>(part, scal);

    pe_kernel<<<(512 * 81 + 255) / 256, 256, 0, stream>>>(pe);

    tokenize_kernel<<<(48 * 512 * 81 + 255) / 256, 256, 0, stream>>>(x, cali, scal, pe, txall);

    qkv2_kernel<<<384, 256, 0, stream>>>(txall, Wq2, Wk2, Wv2, Q2, Kc, Vc);

    attn2_kernel<<<(512 * 9 * 32) / 256, 256, 0, stream>>>(Q2, Kc, Vc, tmp2);

    h2xh_kernel<<<256, 256, 0, stream>>>(tmp2, Wo2, txall, h2, xh);

    qks_kernel<<<256, 256, 0, stream>>>(xh, Wq, Wk, Qs, Ks);

    biasmm_kernel<<<dim3(16, 16), dim3(16, 16), 0, stream>>>(corr, Cv, biasT);

    attn1_kernel<<<576, 256, 0, stream>>>(Qs, Ks, biasT, corr_w, h1tmp);

    h1o_kernel<<<256, 256, 0, stream>>>(h1tmp, Wo1, h2, txall, h_w, matin, st1);

    ff1_kernel<<<dim3(256, 2), 256, 0, stream>>>(matin, st1, g1, b1, ff1_w, ff1_b, f1, st2);

    ff2_kernel<<<512, 256, 0, stream>>>(f1, st2, g2, b2, ff2_w, ff2_b,
                                        matin, st1, g1, b1, t3, st3);

    token_kernel<<<512, 256, 0, stream>>>(t3, st3, g3, b3, tvw, tvb, beta1, basel, a1, a2, fea);

    fc1_kernel<<<64, 256, 0, stream>>>(fea, fc1_w, fc1_b, fch1, st4);

    fc2_kernel<<<32, 256, 0, stream>>>(fch1, st4, bnf1_g, bnf1_b, fc2_w, fc2_b, fch2, st5);

    fc3_kernel<<<1, 128, 0, stream>>>(fch2, st5, bnf2_g, bnf2_b, fc3_w, fc3_b, out);
}

// Round 5
// 519.310 us; speedup vs baseline: 2.4863x; 1.0013x over previous
//
#include <hip/hip_runtime.h>
#include <hip/hip_bf16.h>
#include <math.h>

#define EPSV 1e-5f

// ---------------- sizes ----------------
// B=32 Bc=16 L=2048 TOKEN=40 STRIDE=4 D=81 H=9 dk=9 S=512 FF=256 FC1=512 FC2=256 Y=4

// ---------------- minmax: two-stage ----------------
__global__ void minmax_part(const float* __restrict__ x, float* __restrict__ part) {
    __shared__ float smin[256], smax[256];
    int tid = threadIdx.x;
    float mn = 1e30f, mx = -1e30f;
    for (int i = blockIdx.x * 256 + tid; i < 32 * 2008; i += 64 * 256) {
        int b = i / 2008, c = i % 2008 + 20;
        float v = x[b * 2048 + c];
        mn = fminf(mn, v); mx = fmaxf(mx, v);
    }
    smin[tid] = mn; smax[tid] = mx; __syncthreads();
    for (int off = 128; off > 0; off >>= 1) {
        if (tid < off) { smin[tid] = fminf(smin[tid], smin[tid + off]); smax[tid] = fmaxf(smax[tid], smax[tid + off]); }
        __syncthreads();
    }
    if (tid == 0) { part[blockIdx.x] = smin[0]; part[64 + blockIdx.x] = smax[0]; }
}

__global__ void minmax_fin(const float* __restrict__ part, float* __restrict__ scal) {
    __shared__ float smn[64], smx[64];
    int tid = threadIdx.x;
    smn[tid] = part[tid]; smx[tid] = part[64 + tid]; __syncthreads();
    for (int off = 32; off > 0; off >>= 1) {
        if (tid < off) { smn[tid] = fminf(smn[tid], smn[tid + off]); smx[tid] = fmaxf(smx[tid], smx[tid + off]); }
        __syncthreads();
    }
    if (tid == 0) { scal[0] = smn[0]; scal[1] = smx[0] - smn[0]; }
}

// ---------------- PE table (512 x 81) ----------------
__global__ void pe_kernel(float* __restrict__ pe) {
    int idx = blockIdx.x * blockDim.x + threadIdx.x;
    if (idx >= 512 * 81) return;
    int d = idx % 81, s = idx / 81;
    int j = d >> 1;
    float dv = __expf(-9.210340371976184f * (2.0f * (float)j) / 81.0f);
    float ang = (float)s * dv;
    pe[idx] = (d & 1) ? cosf(ang) : sinf(ang);
}

// ---------------- tokenize + add PE ----------------
__global__ void tokenize_kernel(const float* __restrict__ x, const float* __restrict__ cali,
                                const float* __restrict__ scal, const float* __restrict__ pe,
                                float* __restrict__ txall) {
    int idx = blockIdx.x * blockDim.x + threadIdx.x;
    if (idx >= 48 * 512 * 81) return;
    int d = idx % 81;
    int s = (idx / 81) % 512;
    int r = idx / (81 * 512);
    float xm = scal[0], inv_xs = 1.0f / scal[1];
    int oc = s * 4 + d - 40;
    float val = 0.0f;
    if (oc >= 0 && oc < 2048) {
        float sv = (r < 32) ? x[r * 2048 + oc] : cali[(r - 32) * 2048 + oc];
        val = (sv - xm) * inv_xs;
    }
    txall[idx] = val + pe[s * 81 + d];
}

// ---------------- qkv2: 64 rows/block, W in LDS, 4-row reg tile ----------------
__global__ __launch_bounds__(256) void qkv2_kernel(const float* __restrict__ txall,
                            const float* __restrict__ Wq2, const float* __restrict__ Wk2,
                            const float* __restrict__ Wv2,
                            float* __restrict__ Q2, float* __restrict__ Kc, float* __restrict__ Vc) {
    __shared__ float rows_[64 * 81];
    __shared__ float Wl[6561];
    int blk = blockIdx.x;            // 0..383
    int row0 = blk * 64;             // k*512+s flattened
    int k = row0 >> 9;               // block-uniform
    int s0 = row0 & 511;
    int tid = threadIdx.x;
    for (int i = tid; i < 64 * 81; i += 256) rows_[i] = txall[row0 * 81 + i];
    for (int t = 0; t < 3; t++) {
        if (t == 0 && k >= 32) continue;   // block-uniform
        const float* W = (t == 0) ? Wq2 : (t == 1) ? Wk2 : Wv2;
        __syncthreads();
        for (int i = tid; i < 6561; i += 256) {
            int e = i / 81, hd = i % 81, h = hd / 9, d = hd % 9;
            Wl[i] = W[h * 729 + e * 9 + d];     // Wl[e*81+hd]
        }
        __syncthreads();
        for (int o = tid; o < 16 * 81; o += 256) {
            int r4 = o / 81, hd = o % 81;
            float a0 = 0, a1 = 0, a2 = 0, a3 = 0;
            const float* rp = rows_ + r4 * 4 * 81;
            #pragma unroll 3
            for (int e = 0; e < 81; e++) {
                float w = Wl[e * 81 + hd];
                a0 += rp[e] * w; a1 += rp[81 + e] * w;
                a2 += rp[162 + e] * w; a3 += rp[243 + e] * w;
            }
            int h = hd / 9, d = hd % 9;
            int sb = s0 + r4 * 4;
            float av[4] = {a0, a1, a2, a3};
            #pragma unroll
            for (int j = 0; j < 4; j++) {
                int s = sb + j;
                if (t == 0)      Q2[((s * 9 + h) * 32 + k) * 9 + d] = av[j];
                else if (t == 1) Kc[((s * 9 + h) * 48 + k) * 9 + d] = av[j];
                else             Vc[((s * 9 + h) * 48 + k) * 9 + d] = av[j];
            }
        }
    }
}

// ---------------- attention-2 (masked: key==b or key>=32) ----------------
__global__ void attn2_kernel(const float* __restrict__ Q2, const float* __restrict__ Kc,
                             const float* __restrict__ Vc, float* __restrict__ tmp2) {
    int tid = blockIdx.x * blockDim.x + threadIdx.x;
    if (tid >= 512 * 9 * 32) return;
    int b = tid & 31;
    int h = (tid >> 5) % 9;
    int s = tid / 288;
    const float* q = Q2 + ((s * 9 + h) * 32 + b) * 9;
    float qr[9];
    #pragma unroll
    for (int d = 0; d < 9; d++) qr[d] = q[d];
    const float* Kb = Kc + (s * 9 + h) * 48 * 9;
    const float* Vb = Vc + (s * 9 + h) * 48 * 9;
    float sc[17];
    float m = -1e30f;
    const float inv3 = 1.0f / 3.0f;
    #pragma unroll
    for (int j = 0; j < 17; j++) {
        int k = (j == 0) ? b : 31 + j;
        const float* kp = Kb + k * 9;
        float acc = 0.0f;
        #pragma unroll
        for (int d = 0; d < 9; d++) acc += qr[d] * kp[d];
        acc *= inv3;
        sc[j] = acc; m = fmaxf(m, acc);
    }
    float l = 0.0f, outv[9];
    #pragma unroll
    for (int d = 0; d < 9; d++) outv[d] = 0.0f;
    #pragma unroll
    for (int j = 0; j < 17; j++) {
        float p = __expf(sc[j] - m); l += p;
        int k = (j == 0) ? b : 31 + j;
        const float* vp = Vb + k * 9;
        #pragma unroll
        for (int d = 0; d < 9; d++) outv[d] += p * vp[d];
    }
    float invl = 1.0f / l;
    float* op = tmp2 + (b * 512 + s) * 81 + h * 9;
    #pragma unroll
    for (int d = 0; d < 9; d++) op[d] = outv[d] * invl;
}

// ---------------- h2 = tmp2 @ Wo2 ; xh = tx + h2  (64 rows/block) ----------------
__global__ __launch_bounds__(256) void h2xh_kernel(const float* __restrict__ tmp2,
                            const float* __restrict__ Wo2, const float* __restrict__ txall,
                            float* __restrict__ h2, float* __restrict__ xh) {
    __shared__ float rows_[64 * 81];
    __shared__ float Wl[6561];
    int row0 = blockIdx.x * 64;
    int tid = threadIdx.x;
    for (int i = tid; i < 64 * 81; i += 256) rows_[i] = tmp2[row0 * 81 + i];
    for (int i = tid; i < 6561; i += 256) Wl[i] = Wo2[i];
    __syncthreads();
    for (int o = tid; o < 16 * 81; o += 256) {
        int r4 = o / 81, c = o % 81;
        float a0 = 0, a1 = 0, a2 = 0, a3 = 0;
        const float* rp = rows_ + r4 * 4 * 81;
        #pragma unroll 3
        for (int e = 0; e < 81; e++) {
            float w = Wl[e * 81 + c];
            a0 += rp[e] * w; a1 += rp[81 + e] * w;
            a2 += rp[162 + e] * w; a3 += rp[243 + e] * w;
        }
        float av[4] = {a0, a1, a2, a3};
        #pragma unroll
        for (int j = 0; j < 4; j++) {
            int idx = (row0 + r4 * 4 + j) * 81 + c;
            h2[idx] = av[j];
            xh[idx] = txall[idx] + av[j];
        }
    }
}

// ---------------- Qs/Ks projections (Vs == Qs) ----------------
__global__ __launch_bounds__(256) void qks_kernel(const float* __restrict__ xh,
                           const float* __restrict__ Wq, const float* __restrict__ Wk,
                           float* __restrict__ Qs, float* __restrict__ Ks) {
    __shared__ float rows_[64 * 81];
    __shared__ float Wl[6561];
    int blk = blockIdx.x;            // 0..255
    int row0 = blk * 64;             // b*512+s
    int b = row0 >> 9;
    int s0 = row0 & 511;
    int tid = threadIdx.x;
    for (int i = tid; i < 64 * 81; i += 256) rows_[i] = xh[row0 * 81 + i];
    for (int t = 0; t < 2; t++) {
        const float* W = (t == 0) ? Wq : Wk;
        __syncthreads();
        for (int i = tid; i < 6561; i += 256) {
            int e = i / 81, hd = i % 81, h = hd / 9, d = hd % 9;
            Wl[i] = W[h * 729 + e * 9 + d];
        }
        __syncthreads();
        float* dst = (t == 0) ? Qs : Ks;
        for (int o = tid; o < 16 * 81; o += 256) {
            int r4 = o / 81, hd = o % 81;
            float a0 = 0, a1 = 0, a2 = 0, a3 = 0;
            const float* rp = rows_ + r4 * 4 * 81;
            #pragma unroll 3
            for (int e = 0; e < 81; e++) {
                float w = Wl[e * 81 + hd];
                a0 += rp[e] * w; a1 += rp[81 + e] * w;
                a2 += rp[162 + e] * w; a3 += rp[243 + e] * w;
            }
            int h = hd / 9, d = hd % 9;
            int sb = s0 + r4 * 4;
            float av[4] = {a0, a1, a2, a3};
            #pragma unroll
            for (int j = 0; j < 4; j++)
                dst[((b * 9 + h) * 512 + (sb + j)) * 9 + d] = av[j];
        }
    }
}

// ---------------- biasT = (corr @ Cv)^T / sqrt(S) ----------------
__global__ __launch_bounds__(256) void biasmm_kernel(const float* __restrict__ corr,
                              const float* __restrict__ Cv, float* __restrict__ biasT) {
    __shared__ float As[32][33];
    __shared__ float Bs[32][33];
    int tx = threadIdx.x, ty = threadIdx.y;   // 16 x 16
    int tid = ty * 16 + tx;
    int t0 = blockIdx.y * 32, s0 = blockIdx.x * 32;
    float a00 = 0, a01 = 0, a10 = 0, a11 = 0;
    for (int k0 = 0; k0 < 512; k0 += 32) {
        for (int ii = tid; ii < 1024; ii += 256) {
            int r = ii >> 5, c = ii & 31;
            As[r][c] = Cv[(k0 + r) * 512 + t0 + c];
            Bs[r][c] = corr[(s0 + r) * 512 + k0 + c];
        }
        __syncthreads();
        #pragma unroll
        for (int kk = 0; kk < 32; kk++) {
            float b0 = Bs[tx][kk], b1 = Bs[tx + 16][kk];
            float c0 = As[kk][ty], c1 = As[kk][ty + 16];
            a00 += c0 * b0; a01 += c0 * b1; a10 += c1 * b0; a11 += c1 * b1;
        }
        __syncthreads();
    }
    const float invs = 0.04419417382415922f;   // 1/sqrt(512)
    biasT[(t0 + ty) * 512 + s0 + tx]            = a00 * invs;
    biasT[(t0 + ty) * 512 + s0 + tx + 16]       = a01 * invs;
    biasT[(t0 + ty + 16) * 512 + s0 + tx]       = a10 * invs;
    biasT[(t0 + ty + 16) * 512 + s0 + tx + 16]  = a11 * invs;
}

// ---------------- attention-1: 4 queries/thread, 4-way key split, in-block merge ----------------
// block = (bh, qhalf): 256 threads = 64 q-threads x 4 key-quarters
// thread (qt, kq): queries q = qhalf*256 + qt + j*64 (j=0..3), keys [kq*128, kq*128+128)
__global__ __launch_bounds__(256) void attn1_kernel(const float* __restrict__ Qs,
                                                    const float* __restrict__ Ks,
                                                    const float* __restrict__ biasT,
                                                    const float* __restrict__ cwp,
                                                    float* __restrict__ h1tmp) {
    int blk = blockIdx.x;          // 0..575
    int bh = blk >> 1;             // b*9+h
    int qhalf = blk & 1;
    int b = bh / 9, h = bh % 9;
    __shared__ float sh[12288];    // 48KB: K [512][12] then V [512][12]; reused for merge
    float (*Ksh)[12] = (float(*)[12])sh;
    float (*Vsh)[12] = (float(*)[12])(sh + 6144);
    int tid = threadIdx.x;
    int qt = tid & 63, kq = tid >> 6;
    const float* Kb = Ks + bh * 4608;
    const float* Qb = Qs + bh * 4608;
    for (int i = tid; i < 4608; i += 256) {
        int r = i / 9, c = i % 9;
        Ksh[r][c] = Kb[i];
        Vsh[r][c] = Qb[i];   // Vs == Qs
    }
    __syncthreads();
    // load 4 query vectors from global (L2)
    int q0 = qhalf * 256 + qt;
    float qv[4][9];
    #pragma unroll
    for (int j = 0; j < 4; j++) {
        const float* qp = Qb + (q0 + j * 64) * 9;
        #pragma unroll
        for (int d = 0; d < 9; d++) qv[j][d] = qp[d];
    }
    float cw = cwp[0];
    float c1 = (1.0f - cw) / 3.0f;
    float m[4], l[4], acc[4][9];
    #pragma unroll
    for (int j = 0; j < 4; j++) {
        m[j] = -1e30f; l[j] = 0.0f;
        #pragma unroll
        for (int d = 0; d < 9; d++) acc[j][d] = 0.0f;
    }
    int t0beg = kq * 128;
    for (int t0 = t0beg; t0 < t0beg + 128; t0 += 8) {
        float sc[8][4];
        #pragma unroll
        for (int tt = 0; tt < 8; tt++) {
            const float4* kp = reinterpret_cast<const float4*>(Ksh[t0 + tt]);
            float4 k0 = kp[0], k1 = kp[1], k2 = kp[2];
            const float* brow = biasT + ((t0 + tt) << 9) + q0;
            #pragma unroll
            for (int j = 0; j < 4; j++) {
                float s = qv[j][0] * k0.x + qv[j][1] * k0.y + qv[j][2] * k0.z + qv[j][3] * k0.w
                        + qv[j][4] * k1.x + qv[j][5] * k1.y + qv[j][6] * k1.z + qv[j][7] * k1.w
                        + qv[j][8] * k2.x;
                sc[tt][j] = c1 * s + cw * brow[j * 64];
            }
        }
        // per-query chunk max + rescale
        #pragma unroll
        for (int j = 0; j < 4; j++) {
            float cm = sc[0][j];
            #pragma unroll
            for (int tt = 1; tt < 8; tt++) cm = fmaxf(cm, sc[tt][j]);
            float nm = fmaxf(m[j], cm);
            float f = __expf(m[j] - nm);
            m[j] = nm;
            l[j] *= f;
            #pragma unroll
            for (int d = 0; d < 9; d++) acc[j][d] *= f;
        }
        #pragma unroll
        for (int tt = 0; tt < 8; tt++) {
            const float4* vp = reinterpret_cast<const float4*>(Vsh[t0 + tt]);
            float4 v0 = vp[0], v1 = vp[1], v2 = vp[2];
            #pragma unroll
            for (int j = 0; j < 4; j++) {
                float p = __expf(sc[tt][j] - m[j]);
                l[j] += p;
                acc[j][0] += p * v0.x; acc[j][1] += p * v0.y; acc[j][2] += p * v0.z;
                acc[j][3] += p * v0.w; acc[j][4] += p * v1.x; acc[j][5] += p * v1.y;
                acc[j][6] += p * v1.z; acc[j][7] += p * v1.w; acc[j][8] += p * v2.x;
            }
        }
    }
    // in-block merge of the 4 key-quarter partials (reuse sh: 256*4*11 = 11264 <= 12288)
    __syncthreads();
    #pragma unroll
    for (int j = 0; j < 4; j++) {
        int ql = qt + j * 64;
        float* P = sh + (ql * 4 + kq) * 11;
        P[0] = m[j]; P[1] = l[j];
        #pragma unroll
        for (int d = 0; d < 9; d++) P[2 + d] = acc[j][d];
    }
    __syncthreads();
    {
        int ql = tid;
        const float* P = sh + ql * 44;
        float M = fmaxf(fmaxf(P[0], P[11]), fmaxf(P[22], P[33]));
        float L = 0.0f;
        float o[9];
        #pragma unroll
        for (int d = 0; d < 9; d++) o[d] = 0.0f;
        #pragma unroll
        for (int k = 0; k < 4; k++) {
            const float* Pk = P + k * 11;
            float w = __expf(Pk[0] - M);
            L += w * Pk[1];
            #pragma unroll
            for (int d = 0; d < 9; d++) o[d] += w * Pk[2 + d];
        }
        float invl = 1.0f / L;
        int q = qhalf * 256 + ql;
        float* op = h1tmp + (b * 512 + q) * 81 + h * 9;
        #pragma unroll
        for (int d = 0; d < 9; d++) op[d] = o[d] * invl;
    }
}

// ---------------- matin = (1-hw)*(h1tmp@Wo1) + hw*h2 + tx ; fused st1 partials ----------------
__global__ __launch_bounds__(256) void h1o_kernel(const float* __restrict__ h1tmp,
                           const float* __restrict__ Wo1, const float* __restrict__ h2,
                           const float* __restrict__ txall, const float* __restrict__ hwp,
                           float* __restrict__ matin, float* __restrict__ st1) {
    __shared__ float rows_[64 * 81];
    __shared__ float Wl[6561];
    __shared__ float ssum[81], ssq[81];
    int row0 = blockIdx.x * 64;
    int tid = threadIdx.x;
    if (tid < 81) { ssum[tid] = 0.0f; ssq[tid] = 0.0f; }
    for (int i = tid; i < 64 * 81; i += 256) rows_[i] = h1tmp[row0 * 81 + i];
    for (int i = tid; i < 6561; i += 256) Wl[i] = Wo1[i];
    __syncthreads();
    float hw = hwp[0];
    float onemhw = 1.0f - hw;
    for (int o = tid; o < 16 * 81; o += 256) {
        int r4 = o / 81, c = o % 81;
        float a0 = 0, a1 = 0, a2 = 0, a3 = 0;
        const float* rp = rows_ + r4 * 4 * 81;
        #pragma unroll 3
        for (int e = 0; e < 81; e++) {
            float w = Wl[e * 81 + c];
            a0 += rp[e] * w; a1 += rp[81 + e] * w;
            a2 += rp[162 + e] * w; a3 += rp[243 + e] * w;
        }
        float av[4] = {a0, a1, a2, a3};
        float ls = 0.0f, lq = 0.0f;
        #pragma unroll
        for (int j = 0; j < 4; j++) {
            int idx = (row0 + r4 * 4 + j) * 81 + c;
            float v = onemhw * av[j] + hw * h2[idx] + txall[idx];
            matin[idx] = v;
            ls += v; lq += v * v;
        }
        atomicAdd(&ssum[c], ls);
        atomicAdd(&ssq[c], lq);
    }
    __syncthreads();
    if (tid < 81) {
        atomicAdd(&st1[tid], ssum[tid]);
        atomicAdd(&st1[81 + tid], ssq[tid]);
    }
}

// ---------------- ff1: f1 = relu(bn1(matin) @ ff1_w + b) ; fused st2 partials ----------------
__global__ __launch_bounds__(256) void ff1_kernel(const float* __restrict__ matin,
                           const float* __restrict__ st1, const float* __restrict__ g1,
                           const float* __restrict__ b1, const float* __restrict__ W,
                           const float* __restrict__ bias, float* __restrict__ f1,
                           float* __restrict__ st2) {
    __shared__ float rows_[64 * 81];
    __shared__ float Wl[81 * 128];
    __shared__ float s2s[128], s2q[128];
    int row0 = blockIdx.x * 64;
    int c0 = blockIdx.y * 128;
    int tid = threadIdx.x;
    const float invN = 1.0f / 16384.0f;
    if (tid < 128) { s2s[tid] = 0.0f; s2q[tid] = 0.0f; }
    for (int i = tid; i < 64 * 81; i += 256) {
        int c = i % 81;
        float mean = st1[c] * invN;
        float var = st1[81 + c] * invN - mean * mean;
        rows_[i] = (matin[row0 * 81 + i] - mean) * rsqrtf(var + EPSV) * g1[c] + b1[c];
    }
    for (int i = tid; i < 81 * 128; i += 256) {
        int e = i >> 7, cc = i & 127;
        Wl[i] = W[e * 256 + c0 + cc];
    }
    __syncthreads();
    for (int o = tid; o < 16 * 128; o += 256) {
        int r4 = o >> 7, cc = o & 127;
        float bv = bias[c0 + cc];
        float a0 = bv, a1 = bv, a2 = bv, a3 = bv;
        const float* rp = rows_ + r4 * 4 * 81;
        #pragma unroll 3
        for (int e = 0; e < 81; e++) {
            float w = Wl[(e << 7) + cc];
            a0 += rp[e] * w; a1 += rp[81 + e] * w;
            a2 += rp[162 + e] * w; a3 += rp[243 + e] * w;
        }
        a0 = fmaxf(a0, 0.0f); a1 = fmaxf(a1, 0.0f);
        a2 = fmaxf(a2, 0.0f); a3 = fmaxf(a3, 0.0f);
        int base = (row0 + r4 * 4) * 256 + c0 + cc;
        f1[base]       = a0;
        f1[base + 256] = a1;
        f1[base + 512] = a2;
        f1[base + 768] = a3;
        atomicAdd(&s2s[cc], a0 + a1 + a2 + a3);
        atomicAdd(&s2q[cc], a0 * a0 + a1 * a1 + a2 * a2 + a3 * a3);
    }
    __syncthreads();
    if (tid < 128) {
        atomicAdd(&st2[c0 + tid], s2s[tid]);
        atomicAdd(&st2[256 + c0 + tid], s2q[tid]);
    }
}

// ---------------- ff2: t3 = bn1(matin) + relu(bn2(f1) @ ff2_w + b) ; fused st3 ----------------
__global__ __launch_bounds__(256) void ff2_kernel(const float* __restrict__ f1,
                           const float* __restrict__ st2, const float* __restrict__ g2,
                           const float* __restrict__ b2, const float* __restrict__ W,
                           const float* __restrict__ bias, const float* __restrict__ matin,
                           const float* __restrict__ st1, const float* __restrict__ g1,
                           const float* __restrict__ b1, float* __restrict__ t3,
                           float* __restrict__ st3) {
    __shared__ float rows_[32 * 128];
    __shared__ float Wl[128 * 81];
    __shared__ float s3s[81], s3q[81];
    int row0 = blockIdx.x * 32;
    int tid = threadIdx.x;
    const float invN = 1.0f / 16384.0f;
    if (tid < 81) { s3s[tid] = 0.0f; s3q[tid] = 0.0f; }
    float acc[3][4];
    #pragma unroll
    for (int oi = 0; oi < 3; oi++) {
        int o = tid + oi * 256;
        float bv = (o < 648) ? bias[o % 81] : 0.0f;
        #pragma unroll
        for (int j = 0; j < 4; j++) acc[oi][j] = bv;
    }
    for (int half = 0; half < 2; half++) {
        __syncthreads();
        for (int i = tid; i < 32 * 128; i += 256) {
            int c = half * 128 + (i & 127);
            float mean = st2[c] * invN;
            float var = st2[256 + c] * invN - mean * mean;
            rows_[i] = (f1[(row0 + (i >> 7)) * 256 + c] - mean) * rsqrtf(var + EPSV) * g2[c] + b2[c];
        }
        for (int i = tid; i < 128 * 81; i += 256) Wl[i] = W[half * 128 * 81 + i];
        __syncthreads();
        #pragma unroll
        for (int oi = 0; oi < 3; oi++) {
            int o = tid + oi * 256;
            if (o < 648) {
                int r4 = o / 81, c = o % 81;
                const float* rp = rows_ + r4 * 4 * 128;
                #pragma unroll 4
                for (int e = 0; e < 128; e++) {
                    float w = Wl[e * 81 + c];
                    acc[oi][0] += rp[e] * w;       acc[oi][1] += rp[128 + e] * w;
                    acc[oi][2] += rp[256 + e] * w; acc[oi][3] += rp[384 + e] * w;
                }
            }
        }
    }
    #pragma unroll
    for (int oi = 0; oi < 3; oi++) {
        int o = tid + oi * 256;
        if (o < 648) {
            int r4 = o / 81, c = o % 81;
            float mean = st1[c] * invN;
            float var = st1[81 + c] * invN - mean * mean;
            float rstd = rsqrtf(var + EPSV);
            float ls = 0.0f, lq = 0.0f;
            #pragma unroll
            for (int j = 0; j < 4; j++) {
                int idx = (row0 + r4 * 4 + j) * 81 + c;
                float ma = (matin[idx] - mean) * rstd * g1[c] + b1[c];
                float v = ma + fmaxf(acc[oi][j], 0.0f);
                t3[idx] = v;
                ls += v; lq += v * v;
            }
            atomicAdd(&s3s[c], ls);
            atomicAdd(&s3q[c], lq);
        }
    }
    __syncthreads();
    if (tid < 81) {
        atomicAdd(&st3[tid], s3s[tid]);
        atomicAdd(&st3[81 + tid], s3q[tid]);
    }
}

// ---------------- token pooling: 32 rows/block, 8 lanes/row ----------------
__global__ __launch_bounds__(256) void token_kernel(const float* __restrict__ t3,
                             const float* __restrict__ st3, const float* __restrict__ g3,
                             const float* __restrict__ b3, const float* __restrict__ tvw,
                             const float* __restrict__ tvb, const float* __restrict__ beta1,
                             const float* __restrict__ basel, const float* __restrict__ a1p,
                             const float* __restrict__ a2p, float* __restrict__ fea) {
    __shared__ float rows_[32 * 81];
    __shared__ float Wu[6561];
    __shared__ float Wv[6561];
    int row0 = blockIdx.x * 32;
    int tid = threadIdx.x;
    const float invN = 1.0f / 16384.0f;
    for (int i = tid; i < 32 * 81; i += 256) {
        int c = i % 81;
        float mean = st3[c] * invN;
        float var = st3[81 + c] * invN - mean * mean;
        rows_[i] = (t3[row0 * 81 + i] - mean) * rsqrtf(var + EPSV) * g3[c] + b3[c];
    }
    for (int i = tid; i < 6561; i += 256) { Wu[i] = tvw[i]; Wv[i] = beta1[i]; }
    __syncthreads();
    int r = tid >> 3, j = tid & 7;
    const float* rp = rows_ + r * 81;
    float u[11], v[11];
    #pragma unroll
    for (int dd = 0; dd < 11; dd++) {
        int d = j + dd * 8;
        u[dd] = (d < 81) ? tvb[d] : 0.0f;
        v[dd] = (d < 81) ? 0.0f : -1e30f;
    }
    for (int e = 0; e < 81; e++) {
        float rv = rp[e];
        #pragma unroll
        for (int dd = 0; dd < 11; dd++) {
            int d = j + dd * 8;
            if (d < 81) {
                u[dd] += rv * Wu[e * 81 + d];
                v[dd] += rv * Wv[e * 81 + d];
            }
        }
    }
    float mx = -1e30f;
    #pragma unroll
    for (int dd = 0; dd < 11; dd++) mx = fmaxf(mx, v[dd]);
    #pragma unroll
    for (int msk = 1; msk < 8; msk <<= 1) mx = fmaxf(mx, __shfl_xor(mx, msk, 8));
    float sp = 0.0f, sup = 0.0f;
    #pragma unroll
    for (int dd = 0; dd < 11; dd++) {
        float p = __expf(v[dd] - mx);
        sp += p; sup += u[dd] * p;
    }
    #pragma unroll
    for (int msk = 1; msk < 8; msk <<= 1) {
        sp  += __shfl_xor(sp, msk, 8);
        sup += __shfl_xor(sup, msk, 8);
    }
    if (j == 0) {
        int rg = row0 + r;
        int b = rg >> 9, s = rg & 511;
        fea[rg] = a1p[0] * (sup / sp) + a2p[0] * basel[b * 2048 + s * 4];
    }
}

// ---------------- fc1: relu(fea @ W + b), fused st4 ----------------
__global__ void fc1_kernel(const float* __restrict__ in, const float* __restrict__ W,
                           const float* __restrict__ bias, float* __restrict__ out,
                           float* __restrict__ st) {
    int idx = blockIdx.x * blockDim.x + threadIdx.x;
    if (idx >= 32 * 512) return;
    int b = idx >> 9, j = idx & 511;
    float acc = bias[j];
    const float* ip = in + (b << 9);
    #pragma unroll 8
    for (int k = 0; k < 512; k++) acc += ip[k] * W[k * 512 + j];
    acc = fmaxf(acc, 0.0f);
    out[idx] = acc;
    atomicAdd(&st[j], acc);
    atomicAdd(&st[512 + j], acc * acc);
}

// ---------------- fc2: relu(bn(fch1) @ W + b), fused st5 ----------------
__global__ __launch_bounds__(256) void fc2_kernel(const float* __restrict__ in,
                           const float* __restrict__ st4, const float* __restrict__ g,
                           const float* __restrict__ bb, const float* __restrict__ W,
                           const float* __restrict__ bias, float* __restrict__ out,
                           float* __restrict__ st5) {
    __shared__ float scale[512], shift[512];
    int tid = threadIdx.x;
    for (int k = tid; k < 512; k += 256) {
        float mean = st4[k] * (1.0f / 32.0f);
        float var = st4[512 + k] * (1.0f / 32.0f) - mean * mean;
        float sc_ = rsqrtf(var + EPSV) * g[k];
        scale[k] = sc_;
        shift[k] = bb[k] - mean * sc_;
    }
    __syncthreads();
    int idx = blockIdx.x * 256 + tid;
    if (idx >= 32 * 256) return;
    int b = idx >> 8, j = idx & 255;
    float acc = bias[j];
    const float* ip = in + (b << 9);
    #pragma unroll 8
    for (int k = 0; k < 512; k++) acc += (ip[k] * scale[k] + shift[k]) * W[k * 256 + j];
    acc = fmaxf(acc, 0.0f);
    out[idx] = acc;
    atomicAdd(&st5[j], acc);
    atomicAdd(&st5[256 + j], acc * acc);
}

// ---------------- fc3: tanh(bn(fch2) @ W + b) ----------------
__global__ void fc3_kernel(const float* __restrict__ in, const float* __restrict__ st5,
                           const float* __restrict__ g, const float* __restrict__ bb,
                           const float* __restrict__ W, const float* __restrict__ bias,
                           float* __restrict__ out) {
    __shared__ float scale[256], shift[256];
    int tid = threadIdx.x;   // 128
    for (int k = tid; k < 256; k += 128) {
        float mean = st5[k] * (1.0f / 32.0f);
        float var = st5[256 + k] * (1.0f / 32.0f) - mean * mean;
        float sc_ = rsqrtf(var + EPSV) * g[k];
        scale[k] = sc_;
        shift[k] = bb[k] - mean * sc_;
    }
    __syncthreads();
    int b = tid >> 2, j = tid & 3;
    float acc = bias[j];
    const float* ip = in + (b << 8);
    #pragma unroll 8
    for (int k = 0; k < 256; k++) acc += (ip[k] * scale[k] + shift[k]) * W[k * 4 + j];
    out[tid] = tanhf(acc);
}

// =======================================================================
extern "C" void kernel_launch(void* const* d_in, const int* in_sizes, int n_in,
                              void* d_out, int out_size, void* d_ws, size_t ws_size,
                              hipStream_t stream) {
    const float* x       = (const float*)d_in[0];
    const float* basel   = (const float*)d_in[1];
    const float* cali    = (const float*)d_in[2];
    const float* Wq      = (const float*)d_in[3];
    const float* Wk      = (const float*)d_in[4];
    const float* Wq2     = (const float*)d_in[5];
    const float* Wk2     = (const float*)d_in[6];
    const float* Wv2     = (const float*)d_in[7];
    const float* Cv      = (const float*)d_in[8];
    const float* Wo1     = (const float*)d_in[9];
    const float* Wo2     = (const float*)d_in[10];
    const float* corr_w  = (const float*)d_in[11];
    const float* h_w     = (const float*)d_in[12];
    const float* corr    = (const float*)d_in[13];
    const float* g1      = (const float*)d_in[14];
    const float* b1      = (const float*)d_in[15];
    const float* ff1_w   = (const float*)d_in[16];
    const float* ff1_b   = (const float*)d_in[17];
    const float* g2      = (const float*)d_in[18];
    const float* b2      = (const float*)d_in[19];
    const float* ff2_w   = (const float*)d_in[20];
    const float* ff2_b   = (const float*)d_in[21];
    const float* g3      = (const float*)d_in[22];
    const float* b3      = (const float*)d_in[23];
    const float* tvw     = (const float*)d_in[24];
    const float* tvb     = (const float*)d_in[25];
    const float* beta1   = (const float*)d_in[26];
    const float* a1      = (const float*)d_in[27];
    const float* a2      = (const float*)d_in[28];
    const float* fc1_w   = (const float*)d_in[29];
    const float* fc1_b   = (const float*)d_in[30];
    const float* bnf1_g  = (const float*)d_in[31];
    const float* bnf1_b  = (const float*)d_in[32];
    const float* fc2_w   = (const float*)d_in[33];
    const float* fc2_b   = (const float*)d_in[34];
    const float* bnf2_g  = (const float*)d_in[35];
    const float* bnf2_b  = (const float*)d_in[36];
    const float* fc3_w   = (const float*)d_in[37];
    const float* fc3_b   = (const float*)d_in[38];
    float* out = (float*)d_out;
    float* ws = (float*)d_ws;

    // ---- workspace layout (float offsets) ----
    const size_t SCAL  = 0;         // 2
    const size_t PART  = 16;        // 128
    const size_t ST1   = 512;       // 162
    const size_t ST2   = 768;       // 512
    const size_t ST3   = 1536;      // 162
    const size_t ST4   = 1792;      // 1024
    const size_t ST5   = 2880;      // 512
    const size_t FEA   = 4096;      // 16384
    const size_t FCH1  = 20480;     // 16384
    const size_t FCH2  = 36864;     // 8192
    const size_t PEO   = 45056;     // 41472
    const size_t TX    = 90112;     // 1990656
    const size_t Q2O   = 2080768;   // 1327104   (reused: h1tmp)
    const size_t KCO   = 3407872;   // 1990656   (reused: Qs)
    const size_t VCO   = 5398528;   // 1990656   (reused: Ks)
    const size_t TMP2  = 7389184;   // 1327104   (reused: matin)
    const size_t H2O   = 8716288;   // 1327104   (reused: t3)
    const size_t XHO   = 10043392;  // 1327104
    const size_t BIASO = 11370496;  // 262144
    const size_t F1O   = 11632640;  // 4194304

    float* scal  = ws + SCAL;
    float* part  = ws + PART;
    float* st1   = ws + ST1;
    float* st2   = ws + ST2;
    float* st3   = ws + ST3;
    float* st4   = ws + ST4;
    float* st5   = ws + ST5;
    float* fea   = ws + FEA;
    float* fch1  = ws + FCH1;
    float* fch2  = ws + FCH2;
    float* pe    = ws + PEO;
    float* txall = ws + TX;
    float* Q2    = ws + Q2O;
    float* Kc    = ws + KCO;
    float* Vc    = ws + VCO;
    float* tmp2  = ws + TMP2;
    float* h2    = ws + H2O;
    float* xh    = ws + XHO;
    float* biasT = ws + BIASO;
    float* f1    = ws + F1O;
    float* h1tmp = Q2;     // reuse
    float* Qs    = Kc;     // reuse
    float* Ks    = Vc;     // reuse
    float* matin = tmp2;   // reuse
    float* t3    = h2;     // reuse

    // zero scal/part/stats region — capture-safe
    hipMemsetAsync(ws, 0, 4096 * sizeof(float), stream);

    minmax_part<<<64, 256, 0, stream>>>(x, part);
    minmax_fin<<<1, 64, 0, stream>>>(part, scal);

    pe_kernel<<<(512 * 81 + 255) / 256, 256, 0, stream>>>(pe);

    tokenize_kernel<<<(48 * 512 * 81 + 255) / 256, 256, 0, stream>>>(x, cali, scal, pe, txall);

    qkv2_kernel<<<384, 256, 0, stream>>>(txall, Wq2, Wk2, Wv2, Q2, Kc, Vc);

    attn2_kernel<<<(512 * 9 * 32) / 256, 256, 0, stream>>>(Q2, Kc, Vc, tmp2);

    h2xh_kernel<<<256, 256, 0, stream>>>(tmp2, Wo2, txall, h2, xh);

    qks_kernel<<<256, 256, 0, stream>>>(xh, Wq, Wk, Qs, Ks);

    biasmm_kernel<<<dim3(16, 16), dim3(16, 16), 0, stream>>>(corr, Cv, biasT);

    attn1_kernel<<<576, 256, 0, stream>>>(Qs, Ks, biasT, corr_w, h1tmp);

    h1o_kernel<<<256, 256, 0, stream>>>(h1tmp, Wo1, h2, txall, h_w, matin, st1);

    ff1_kernel<<<dim3(256, 2), 256, 0, stream>>>(matin, st1, g1, b1, ff1_w, ff1_b, f1, st2);

    ff2_kernel<<<512, 256, 0, stream>>>(f1, st2, g2, b2, ff2_w, ff2_b,
                                        matin, st1, g1, b1, t3, st3);

    token_kernel<<<512, 256, 0, stream>>>(t3, st3, g3, b3, tvw, tvb, beta1, basel, a1, a2, fea);

    fc1_kernel<<<64, 256, 0, stream>>>(fea, fc1_w, fc1_b, fch1, st4);

    fc2_kernel<<<32, 256, 0, stream>>>(fch1, st4, bnf1_g, bnf1_b, fc2_w, fc2_b, fch2, st5);

    fc3_kernel<<<1, 128, 0, stream>>>(fch2, st5, bnf2_g, bnf2_b, fc3_w, fc3_b, out);
}